// Round 15
// baseline (354.994 us; speedup 1.0000x reference)
//
#include <hip/hip_runtime.h>
#include <cstdint>
#include <cstddef>

typedef float f32x4 __attribute__((ext_vector_type(4)));
typedef short s16x8 __attribute__((ext_vector_type(8)));
typedef unsigned short u16;

#define EPS 1e-6f

__device__ __forceinline__ u16 f2bf(float f) {
    unsigned u = __float_as_uint(f);
    u += 0x7FFFu + ((u >> 16) & 1u);
    return (u16)(u >> 16);
}
__device__ __forceinline__ float bf2f(u16 u) {
    return __uint_as_float(((unsigned)u) << 16);
}

typedef const __attribute__((address_space(1))) void cg_void;
typedef __attribute__((address_space(3))) void l_void;
__device__ __forceinline__ void async16(void* dst_lds, const void* src_g) {
    __builtin_amdgcn_global_load_lds((cg_void*)src_g, (l_void*)dst_lds, 16, 0, 0);
}

#define BARRIER() do { asm volatile("" ::: "memory"); \
                       __builtin_amdgcn_s_barrier();  \
                       asm volatile("" ::: "memory"); } while (0)

// ---------------------------------------------------------------------------
// prep_cast: [0,3072) weight transpose+cast 64x64; [3072,7168) q cast.
// (R13-verified. Kept SPLIT from down_mfma: R14's merge cost ~40us via
// makespan imbalance between latency-bound down blocks and BW-bound casts.)
// ---------------------------------------------------------------------------
__global__ __launch_bounds__(256) void prep_cast(
    const float* __restrict__ q, u16* __restrict__ qb,
    const float* __restrict__ w0, const float* __restrict__ w1,
    const float* __restrict__ w2, u16* __restrict__ o0,
    u16* __restrict__ o1, u16* __restrict__ o2)
{
    __shared__ u16 tl[64 * 68];
    const int bid = blockIdx.x;
    const int tid = threadIdx.x;
    if (bid < 3072) {
        int which = bid >> 10;
        int t = bid & 1023;
        const float* in = which == 0 ? w0 : which == 1 ? w1 : w2;
        u16* out        = which == 0 ? o0 : which == 1 ? o1 : o2;
        int bx = (t & 31) * 64, by = (t >> 5) * 64;
        int tx = tid & 63, ty = tid >> 6;
        #pragma unroll 4
        for (int i = ty; i < 64; i += 4)
            tl[tx * 68 + i] = f2bf(in[(size_t)(by + i) * 2048 + bx + tx]);
        __syncthreads();
        int srow = tid >> 2, sq = tid & 3;
        const u16* lp = &tl[srow * 68 + sq * 16];
        u16* op = &out[(size_t)(bx + srow) * 2048 + by + sq * 16];
        #pragma unroll
        for (int j8 = 0; j8 < 4; ++j8)
            *(short4*)(op + j8 * 4) = *(const short4*)(lp + j8 * 4);
    } else {
        int cb = bid - 3072;
        size_t base = (size_t)cb * 256 + tid;
        #pragma unroll
        for (int it = 0; it < 8; ++it) {
            size_t i = base + (size_t)it * 1048576;
            float4 f = ((const float4*)q)[i];
            ushort4 o;
            o.x = f2bf(f.x); o.y = f2bf(f.y); o.z = f2bf(f.z); o.w = f2bf(f.w);
            ((ushort4*)qb)[i] = o;
        }
    }
}

// ---------------------------------------------------------------------------
// down_mfma: kds[b,kk,d] = sum_s W[kk,s]*x[b,s,d]. grid 2048 (64-col slices).
// (R13-verified, separate launch.)
// ---------------------------------------------------------------------------
__global__ __launch_bounds__(256) void down_mfma(
    const float* __restrict__ kin, const float* __restrict__ vin,
    const float* __restrict__ wdk, const float* __restrict__ wdv,
    u16* __restrict__ kds, u16* __restrict__ vds)
{
    __shared__ __align__(16) u16 At[64 * 32];
    __shared__ __align__(16) u16 Bt[64 * 40];
    const int bid = blockIdx.x;
    const int tid = threadIdx.x;
    const int sel = bid >> 10, rem = bid & 1023;
    const int b = rem >> 5, d0 = (rem & 31) << 6;
    const float* x  = sel ? vin : kin;
    const float* wd = sel ? wdv : wdk;
    u16* outp       = sel ? vds : kds;
    const int w = tid >> 6, l = tid & 63, l16 = l & 15, k8 = l >> 4;
    f32x4 acc[4];
    #pragma unroll
    for (int fm = 0; fm < 4; ++fm) acc[fm] = (f32x4){0.f, 0.f, 0.f, 0.f};
    for (int s0 = 0; s0 < 512; s0 += 32) {
        __syncthreads();
        for (int c = tid; c < 512; c += 256) {
            int kkr = c >> 3, sc = (c & 7) << 2;
            float4 f = *(const float4*)&wd[kkr * 512 + s0 + sc];
            u16* dst = &At[kkr * 32 + sc];
            dst[0] = f2bf(f.x); dst[1] = f2bf(f.y); dst[2] = f2bf(f.z); dst[3] = f2bf(f.w);
        }
        {
            int c = tid;
            int sp = c >> 4, dq = (c & 15) << 2;
            int srow = sp << 1;
            const float* xp = &x[((size_t)(b * 512) + s0 + srow) * 2048 + d0 + dq];
            float4 f0 = *(const float4*)xp;
            float4 f1 = *(const float4*)(xp + 2048);
            int col = srow ^ ((c & 3) << 3);
            unsigned p0 = (unsigned)f2bf(f0.x) | ((unsigned)f2bf(f1.x) << 16);
            unsigned p1 = (unsigned)f2bf(f0.y) | ((unsigned)f2bf(f1.y) << 16);
            unsigned p2 = (unsigned)f2bf(f0.z) | ((unsigned)f2bf(f1.z) << 16);
            unsigned p3 = (unsigned)f2bf(f0.w) | ((unsigned)f2bf(f1.w) << 16);
            *(unsigned*)&Bt[(dq + 0) * 40 + col] = p0;
            *(unsigned*)&Bt[(dq + 1) * 40 + col] = p1;
            *(unsigned*)&Bt[(dq + 2) * 40 + col] = p2;
            *(unsigned*)&Bt[(dq + 3) * 40 + col] = p3;
        }
        __syncthreads();
        s16x8 af[4], bfr;
        #pragma unroll
        for (int fm = 0; fm < 4; ++fm)
            af[fm] = *(const s16x8*)&At[(fm * 16 + l16) * 32 + k8 * 8];
        bfr = *(const s16x8*)&Bt[((w << 4) + l16) * 40 + ((k8 ^ (l16 >> 2)) << 3)];
        #pragma unroll
        for (int fm = 0; fm < 4; ++fm)
            acc[fm] = __builtin_amdgcn_mfma_f32_16x16x32_bf16(af[fm], bfr, acc[fm], 0, 0, 0);
    }
    #pragma unroll
    for (int fm = 0; fm < 4; ++fm)
        #pragma unroll
        for (int j = 0; j < 4; ++j) {
            int r = fm * 16 + k8 * 4 + j;
            int c = (w << 4) + l16;
            outp[((size_t)(b * 64 + r)) * 2048 + d0 + c] = f2bf(acc[fm][j]);
        }
}

// ---------------------------------------------------------------------------
// 128x128 bf16 GEMM, dual: z=0: phik=elu(kds@wkT)+1; z=1: vals=vds@wvT
// ---------------------------------------------------------------------------
__global__ __launch_bounds__(256) void gemm128_dual(
    const u16* __restrict__ A0, const u16* __restrict__ B0, u16* __restrict__ C0,
    const u16* __restrict__ A1, const u16* __restrict__ B1, u16* __restrict__ C1)
{
    const u16* A  = blockIdx.z ? A1 : A0;
    const u16* BT = blockIdx.z ? B1 : B0;
    u16* C        = blockIdx.z ? C1 : C0;
    const bool elu = (blockIdx.z == 0);
    const int K = 2048;

    __shared__ __align__(16) u16 lds[2][8192];
    const int tid = threadIdx.x;
    const int w = tid >> 6, l = tid & 63;
    const int wm = w >> 1, wn = w & 1;
    const int l16 = l & 15, k8 = l >> 4;
    const int sr = (w << 4) + (l >> 2);
    const int sc = (l & 3) << 3;
    const int row0 = blockIdx.y * 128, col0 = blockIdx.x * 128;
    const int nk = K >> 5;
    f32x4 acc[4][4] = {};

#define STAGE(buf, kt) do {                                                        \
        int kk0 = (kt) << 5;                                                       \
        _Pragma("unroll")                                                          \
        for (int i = 0; i < 2; ++i) {                                              \
            const u16* ga = A + (size_t)(row0 + i * 64 + sr) * K + kk0 + sc;       \
            async16(&lds[buf][i * 2048 + (w << 9)], ga);                           \
            const u16* gb = BT + (size_t)(col0 + i * 64 + sr) * K + kk0 + sc;      \
            async16(&lds[buf][4096 + i * 2048 + (w << 9)], gb);                    \
        }                                                                          \
    } while (0)

    STAGE(0, 0);
    asm volatile("s_waitcnt vmcnt(0)" ::: "memory");
    __syncthreads();
    int cur = 0;
    for (int kt = 0; kt < nk; ++kt) {
        if (kt + 1 < nk) STAGE(cur ^ 1, kt + 1);
        s16x8 af[4], bfr[4];
        const u16* Ab = &lds[cur][0];
        const u16* Bb = &lds[cur][4096];
        #pragma unroll
        for (int fm = 0; fm < 4; ++fm)
            af[fm] = *(const s16x8*)&Ab[((wm << 6) + (fm << 4) + l16) * 32 + (k8 << 3)];
        #pragma unroll
        for (int fn = 0; fn < 4; ++fn)
            bfr[fn] = *(const s16x8*)&Bb[((wn << 6) + (fn << 4) + l16) * 32 + (k8 << 3)];
        #pragma unroll
        for (int fm = 0; fm < 4; ++fm)
            #pragma unroll
            for (int fn = 0; fn < 4; ++fn)
                acc[fm][fn] = __builtin_amdgcn_mfma_f32_16x16x32_bf16(af[fm], bfr[fn], acc[fm][fn], 0, 0, 0);
        __syncthreads();
        cur ^= 1;
    }
#undef STAGE

    #pragma unroll
    for (int fm = 0; fm < 4; ++fm)
        #pragma unroll
        for (int j = 0; j < 4; ++j) {
            int r = row0 + (wm << 6) + (fm << 4) + (k8 << 2) + j;
            size_t rbase = (size_t)r * 2048;
            #pragma unroll
            for (int fn = 0; fn < 4; ++fn) {
                int c = col0 + (wn << 6) + (fn << 4) + l16;
                float x = acc[fm][fn][j];
                if (elu) x = x > 0.0f ? x + 1.0f : __expf(x);
                C[rbase + c] = f2bf(x);
            }
        }
}

// ---------------------------------------------------------------------------
// s & z per (b,n): sT bf16 [B,N,128,128], z fp32 [B,N,128]  (R8-verified)
// ---------------------------------------------------------------------------
__global__ __launch_bounds__(256) void sz_kernel(
    const u16* __restrict__ phik, const u16* __restrict__ vals,
    u16* __restrict__ sT, float* __restrict__ z)
{
    int b = blockIdx.x >> 4, n = blockIdx.x & 15;
    __shared__ __align__(16) u16 pk[64 * 128];
    __shared__ __align__(16) u16 vv[64 * 128];
    int tid = threadIdx.x;
    for (int i = tid; i < 1024; i += 256) {
        int r = i >> 4, c8 = (i & 15) << 3;
        size_t g = ((size_t)(b * 64 + r)) * 2048 + n * 128 + c8;
        ((s16x8*)pk)[i] = *(const s16x8*)&phik[g];
        ((s16x8*)vv)[i] = *(const s16x8*)&vals[g];
    }
    __syncthreads();
    if (tid < 128) {
        float s = 0.0f;
        for (int kk = 0; kk < 64; ++kk) s += bf2f(pk[kk * 128 + tid]);
        z[((size_t)(b * 16 + n)) * 128 + tid] = s;
    }
    int hg = tid >> 4, dg = tid & 15;
    int h0 = hg * 8, d0 = dg * 8;
    float acc[8][8] = {};
    for (int kk = 0; kk < 64; ++kk) {
        s16x8 vr = *(const s16x8*)&vv[kk * 128 + h0];
        s16x8 pr = *(const s16x8*)&pk[kk * 128 + d0];
        float va[8], pa[8];
        #pragma unroll
        for (int i = 0; i < 8; ++i) { va[i] = bf2f((u16)vr[i]); pa[i] = bf2f((u16)pr[i]); }
        #pragma unroll
        for (int i = 0; i < 8; ++i)
            #pragma unroll
            for (int j = 0; j < 8; ++j)
                acc[i][j] += va[i] * pa[j];
    }
    size_t base = ((size_t)(b * 16 + n)) * 16384;
    #pragma unroll
    for (int i = 0; i < 8; ++i) {
        u16 row[8];
        #pragma unroll
        for (int j = 0; j < 8; ++j) row[j] = f2bf(acc[i][j]);
        *(s16x8*)&sT[base + (size_t)(h0 + i) * 128 + d0] = *(s16x8*)row;
    }
}

// ---------------------------------------------------------------------------
// gemm256_qs: 256x256 8-phase bf16 GEMM (phi_q) with FUSED qs epilogue v2.
// (R14-verified: P-half + sT tile staged in LDS, qz via broadcast-z MFMA.)
// ---------------------------------------------------------------------------
__global__ __launch_bounds__(512, 2) void gemm256_qs(
    const u16* __restrict__ A, const u16* __restrict__ BT,
    const u16* __restrict__ sT, const float* __restrict__ z,
    float* __restrict__ outp)
{
    const int K = 2048, NT = 32, nbn = 8;
    __shared__ __align__(16) u16 lds[8][8192];
    const int tid = threadIdx.x;
    const int w = tid >> 6, l = tid & 63;
    const int wm = w >> 2, wn = w & 3;
    const int l16 = l & 15, k8 = l >> 4;

    const int nwg = gridDim.x;
    int wg = blockIdx.x;
    if ((nwg & 7) == 0) wg = (wg & 7) * (nwg >> 3) + (wg >> 3);
    const int row0 = (wg / nbn) << 8, col0 = (wg % nbn) << 8;

    const int lr  = l >> 3;
    const int scb = (((l & 7) ^ lr) << 4);
    const int swzr = (l16 & 7) << 4;

#define PANEL(s, m, h) (&lds[((s) << 2) | ((m) << 1) | (h)][0])

#define STG(pan, G, prow0, kk0) do {                                             \
        _Pragma("unroll")                                                        \
        for (int i_ = 0; i_ < 2; ++i_) {                                         \
            int seg_ = w + (i_ << 3);                                            \
            const u16* src_ = (G) + (size_t)((prow0) + (seg_ << 3) + lr) * K     \
                              + (kk0) + (scb >> 1);                              \
            async16((pan) + (seg_ << 9), src_);                                  \
        } } while (0)

#define LDA(slot, mh) do { const u16* p_ = PANEL(slot, 0, mh);                   \
        _Pragma("unroll")                                                        \
        for (int fm_ = 0; fm_ < 4; ++fm_)                                        \
        _Pragma("unroll")                                                        \
        for (int ks_ = 0; ks_ < 2; ++ks_)                                        \
            Af[fm_][ks_] = *(const s16x8*)(p_ + (wm * 64 + fm_ * 16 + l16) * 64  \
                           + (((ks_ * 64 + k8 * 16) ^ swzr) >> 1)); } while (0)

#define LDB(slot, nh, dst) do { const u16* p_ = PANEL(slot, 1, nh);              \
        _Pragma("unroll")                                                        \
        for (int fn_ = 0; fn_ < 2; ++fn_)                                        \
        _Pragma("unroll")                                                        \
        for (int ks_ = 0; ks_ < 2; ++ks_)                                        \
            dst[fn_][ks_] = *(const s16x8*)(p_ + (wn * 32 + fn_ * 16 + l16) * 64 \
                           + (((ks_ * 64 + k8 * 16) ^ swzr) >> 1)); } while (0)

#define MM(mh, nh, BF) do {                                                      \
        __builtin_amdgcn_s_setprio(1);                                           \
        _Pragma("unroll")                                                        \
        for (int fm_ = 0; fm_ < 4; ++fm_)                                        \
        _Pragma("unroll")                                                        \
        for (int fn_ = 0; fn_ < 2; ++fn_)                                        \
        _Pragma("unroll")                                                        \
        for (int ks_ = 0; ks_ < 2; ++ks_)                                        \
            acc[mh][nh][fm_][fn_] = __builtin_amdgcn_mfma_f32_16x16x32_bf16(     \
                Af[fm_][ks_], BF[fn_][ks_], acc[mh][nh][fm_][fn_], 0, 0, 0);     \
        __builtin_amdgcn_s_setprio(0); } while (0)

#define TILE(t, cur, nxt, BFc, BFn) do {                                         \
        LDA(cur, 0);                                                             \
        if ((t) + 1 < NT) STG(PANEL(nxt, 0, 1), A, row0 + 128, ((t) + 1) << 6);  \
        BARRIER(); MM(0, 0, BFc); BARRIER();                                     \
        LDB(cur, 1, Bf1);                                                        \
        if ((t) + 2 < NT) STG(PANEL(cur, 0, 0), A, row0, ((t) + 2) << 6);        \
        BARRIER(); MM(0, 1, Bf1); BARRIER();                                     \
        LDA(cur, 1);                                                             \
        if ((t) + 2 < NT) STG(PANEL(cur, 1, 0), BT, col0, ((t) + 2) << 6);       \
        BARRIER(); MM(1, 1, Bf1); BARRIER();                                     \
        if ((t) + 2 < NT) STG(PANEL(cur, 1, 1), BT, col0 + 128, ((t) + 2) << 6); \
        BARRIER(); MM(1, 0, BFc);                                                \
        if ((t) == NT - 2)     asm volatile("s_waitcnt vmcnt(0)" ::: "memory");  \
        else if ((t) < NT - 2) asm volatile("s_waitcnt vmcnt(6)" ::: "memory");  \
        BARRIER();                                                               \
        if ((t) + 1 < NT) LDB(nxt, 0, BFn);                                      \
    } while (0)

    f32x4 acc[2][2][4][2] = {};
    s16x8 Af[4][2], Bf0a[2][2], Bf0b[2][2], Bf1[2][2];

    STG(PANEL(0, 0, 0), A,  row0,       0);
    STG(PANEL(0, 1, 0), BT, col0,       0);
    STG(PANEL(0, 1, 1), BT, col0 + 128, 0);
    STG(PANEL(0, 0, 1), A,  row0 + 128, 0);
    STG(PANEL(1, 0, 0), A,  row0,       64);
    STG(PANEL(1, 1, 0), BT, col0,       64);
    STG(PANEL(1, 1, 1), BT, col0 + 128, 64);
    asm volatile("s_waitcnt vmcnt(6)" ::: "memory");
    BARRIER();
    LDB(0, 0, Bf0a);

    for (int t = 0; t < NT; t += 2) {
        TILE(t,     0, 1, Bf0a, Bf0b);
        TILE(t + 1, 1, 0, Bf0b, Bf0a);
    }
#undef PANEL
#undef STG
#undef LDA
#undef LDB
#undef MM
#undef TILE

    // ---- fused qs epilogue v2 ----
    const int b = row0 >> 9;
    const int n0 = col0 >> 7;
    u16* Ph  = &lds[0][0];              // [256][128] swizzled P half
    u16* sTl = &lds[4][0];              // [128][128] swizzled sT tile

    #pragma unroll
    for (int nsel = 0; nsel < 2; ++nsel) {
        #pragma unroll
        for (int mh = 0; mh < 2; ++mh)
            #pragma unroll
            for (int fm = 0; fm < 4; ++fm)
                #pragma unroll
                for (int j = 0; j < 4; ++j) {
                    int rr = mh * 128 + wm * 64 + fm * 16 + k8 * 4 + j;
                    int rowbase = rr << 7;
                    int msk = ((rr >> 2) & 7) << 4;
                    #pragma unroll
                    for (int fn = 0; fn < 2; ++fn) {
                        int cc = wn * 32 + fn * 16 + l16;
                        float x = acc[mh][nsel][fm][fn][j];
                        x = x > 0.0f ? x + 1.0f : __expf(x);
                        Ph[rowbase + (cc ^ msk)] = f2bf(x);
                    }
                }
        {
            const size_t stb = ((size_t)(b * 16 + n0 + nsel)) << 14;
            #pragma unroll
            for (int it = 0; it < 4; ++it) {
                int g = (it << 12) + (tid << 3);
                int row = g >> 7;
                int ch8 = (g >> 3) & 15;
                const u16* src = sT + stb + (row << 7) + ((ch8 ^ (row & 7)) << 3);
                async16(&sTl[g], src);
            }
        }
        __syncthreads();

        const int nn = n0 + nsel;
        const float* zp0 = z + ((size_t)(b * 16 + nn) << 7);
        s16x8 Bz[4];
        #pragma unroll
        for (int ks = 0; ks < 4; ++ks) {
            const float* zp = zp0 + (ks << 5) + (k8 << 3);
            float4 f0 = *(const float4*)zp;
            float4 f1 = *(const float4*)(zp + 4);
            u16 tmp[8] = { f2bf(f0.x), f2bf(f0.y), f2bf(f0.z), f2bf(f0.w),
                           f2bf(f1.x), f2bf(f1.y), f2bf(f1.z), f2bf(f1.w) };
            Bz[ks] = *(const s16x8*)tmp;
        }

        s16x8 Af2[2][4];
        #pragma unroll
        for (int fm2 = 0; fm2 < 2; ++fm2) {
            int rr = (w << 5) + (fm2 << 4) + l16;
            int rowbase = rr << 7;
            int msk = ((rr >> 2) & 7) << 4;
            #pragma unroll
            for (int ks = 0; ks < 4; ++ks) {
                int cc = (ks << 5) + (k8 << 3);
                Af2[fm2][ks] = *(const s16x8*)&Ph[rowbase + (cc ^ msk)];
            }
        }

        f32x4 accz[2] = {};
        #pragma unroll
        for (int fm2 = 0; fm2 < 2; ++fm2)
            #pragma unroll
            for (int ks = 0; ks < 4; ++ks)
                accz[fm2] = __builtin_amdgcn_mfma_f32_16x16x32_bf16(Af2[fm2][ks], Bz[ks], accz[fm2], 0, 0, 0);

        f32x4 acc2[2][8] = {};
        #pragma unroll
        for (int fn = 0; fn < 8; ++fn) {
            s16x8 Bfr[4];
            #pragma unroll
            for (int ks = 0; ks < 4; ++ks) {
                int rw = (fn << 4) + l16;
                Bfr[ks] = *(const s16x8*)&sTl[(rw << 7)
                            + (((ks << 5) + (k8 << 3)) ^ ((rw & 7) << 3))];
            }
            #pragma unroll
            for (int fm2 = 0; fm2 < 2; ++fm2)
                #pragma unroll
                for (int ks = 0; ks < 4; ++ks)
                    acc2[fm2][fn] = __builtin_amdgcn_mfma_f32_16x16x32_bf16(Af2[fm2][ks], Bfr[ks], acc2[fm2][fn], 0, 0, 0);
        }

        #pragma unroll
        for (int fm2 = 0; fm2 < 2; ++fm2)
            #pragma unroll
            for (int j = 0; j < 4; ++j) {
                int grow = row0 + (w << 5) + (fm2 << 4) + (k8 << 2) + j;
                float rq = 1.0f / (accz[fm2][j] + EPS);
                size_t ob = (size_t)grow * 2048 + col0 + (nsel << 7);
                #pragma unroll
                for (int fn = 0; fn < 8; ++fn)
                    outp[ob + (fn << 4) + l16] = acc2[fm2][fn][j] * rq;
            }
        __syncthreads();
    }
}

// ---------------------------------------------------------------------------
extern "C" void kernel_launch(void* const* d_in, const int* in_sizes, int n_in,
                              void* d_out, int out_size, void* d_ws, size_t ws_size,
                              hipStream_t stream) {
    (void)in_sizes; (void)n_in; (void)out_size; (void)ws_size;
    const float* q   = (const float*)d_in[0];
    const float* k   = (const float*)d_in[1];
    const float* v   = (const float*)d_in[2];
    const float* wq  = (const float*)d_in[3];
    const float* wk  = (const float*)d_in[4];
    const float* wv  = (const float*)d_in[5];
    const float* kdw = (const float*)d_in[6];
    const float* vdw = (const float*)d_in[7];
    float* out = (float*)d_out;

    char* p = (char*)d_ws;
    u16* qb   = (u16*)p; p += (size_t)16384 * 2048 * 2;
    u16* wqT  = (u16*)p; p += (size_t)2048 * 2048 * 2;
    u16* wkT  = (u16*)p; p += (size_t)2048 * 2048 * 2;
    u16* wvT  = (u16*)p; p += (size_t)2048 * 2048 * 2;
    u16* kds  = (u16*)p; p += (size_t)2048 * 2048 * 2;
    u16* vds  = (u16*)p; p += (size_t)2048 * 2048 * 2;
    u16* phik = (u16*)p; p += (size_t)2048 * 2048 * 2;
    u16* vals = (u16*)p; p += (size_t)2048 * 2048 * 2;
    u16* sT   = (u16*)p; p += (size_t)512 * 128 * 128 * 2;
    float* z  = (float*)p; p += (size_t)512 * 128 * 4;

    prep_cast<<<7168, 256, 0, stream>>>(q, qb, wq, wk, wv, wqT, wkT, wvT);
    down_mfma<<<2048, 256, 0, stream>>>(k, v, kdw, vdw, kds, vds);
    gemm128_dual<<<dim3(16, 16, 2), 256, 0, stream>>>(kds, wkT, phik, vds, wvT, vals);
    sz_kernel<<<512, 256, 0, stream>>>(phik, vals, sT, z);
    gemm256_qs<<<512, 512, 0, stream>>>(qb, wqT, sT, z, out);
}

// Round 16
// 347.115 us; speedup vs baseline: 1.0227x; 1.0227x over previous
//
#include <hip/hip_runtime.h>
#include <cstdint>
#include <cstddef>

typedef float f32x4 __attribute__((ext_vector_type(4)));
typedef short s16x8 __attribute__((ext_vector_type(8)));
typedef unsigned short u16;

#define EPS 1e-6f

__device__ __forceinline__ u16 f2bf(float f) {
    unsigned u = __float_as_uint(f);
    u += 0x7FFFu + ((u >> 16) & 1u);
    return (u16)(u >> 16);
}
__device__ __forceinline__ float bf2f(u16 u) {
    return __uint_as_float(((unsigned)u) << 16);
}

typedef const __attribute__((address_space(1))) void cg_void;
typedef __attribute__((address_space(3))) void l_void;
__device__ __forceinline__ void async16(void* dst_lds, const void* src_g) {
    __builtin_amdgcn_global_load_lds((cg_void*)src_g, (l_void*)dst_lds, 16, 0, 0);
}

#define BARRIER() do { asm volatile("" ::: "memory"); \
                       __builtin_amdgcn_s_barrier();  \
                       asm volatile("" ::: "memory"); } while (0)

// ---------------------------------------------------------------------------
// prep_down: all preprocessing in one launch (9216 blocks) — R14-verified
// merge (graph-total A/B: merged 344.9 vs split 355.0; rocprof per-dispatch
// times are inflated and NOT additive vs graph totals).
//   [0,2048):     downsample via MFMA (64-col d-slices) + T14 reg-prefetch:
//                 loads for step t+1 issue between the barriers, wait lands
//                 behind sync_B + ds_read/MFMA + sync_A. Single LDS buffer
//                 (R7 lesson: dbuf cost occupancy).
//   [2048,5120):  weight transpose+cast 64x64 tiles
//   [5120,9216):  q cast fp32->bf16
// ---------------------------------------------------------------------------
__global__ __launch_bounds__(256) void prep_down(
    const float* __restrict__ q, u16* __restrict__ qb,
    const float* __restrict__ w0, const float* __restrict__ w1,
    const float* __restrict__ w2, u16* __restrict__ o0,
    u16* __restrict__ o1, u16* __restrict__ o2,
    const float* __restrict__ kin, const float* __restrict__ vin,
    const float* __restrict__ wdk, const float* __restrict__ wdv,
    u16* __restrict__ kds, u16* __restrict__ vds)
{
    __shared__ __align__(16) char smem[9216];
    const int bid = blockIdx.x;
    const int tid = threadIdx.x;

    if (bid < 2048) {
        // ---------------- downsample via MFMA (T14 reg-prefetch) ----------------
        u16* At = (u16*)smem;            // [64][32]
        u16* Bt = (u16*)(smem + 4096);   // [64][40] XOR-swizzled
        const int sel = bid >> 10, rem = bid & 1023;
        const int b = rem >> 5, d0 = (rem & 31) << 6;
        const float* x  = sel ? vin : kin;
        const float* wd = sel ? wdv : wdk;
        u16* outp       = sel ? vds : kds;
        const int w = tid >> 6, l = tid & 63, l16 = l & 15, k8 = l >> 4;

        // prefetch registers
        float4 wfa0, wfa1, xf0, xf1;
        const int kkr0 = tid >> 3,          sc0 = (tid & 7) << 2;
        const int kkr1 = (tid + 256) >> 3,  sc1 = (tid & 7) << 2;   // (tid+256)&7 == tid&7
        const int sp = tid >> 4, dq = (tid & 15) << 2;
        const int srow = sp << 1;
        const int colB = srow ^ ((tid & 3) << 3);

#define DLOAD(s0) do {                                                            \
        wfa0 = *(const float4*)&wd[kkr0 * 512 + (s0) + sc0];                      \
        wfa1 = *(const float4*)&wd[kkr1 * 512 + (s0) + sc1];                      \
        const float* xp_ = &x[((size_t)(b * 512) + (s0) + srow) * 2048 + d0 + dq];\
        xf0 = *(const float4*)xp_;                                                \
        xf1 = *(const float4*)(xp_ + 2048);                                       \
    } while (0)

#define DWRITE() do {                                                             \
        u16* dstA0 = &At[kkr0 * 32 + sc0];                                        \
        dstA0[0] = f2bf(wfa0.x); dstA0[1] = f2bf(wfa0.y);                         \
        dstA0[2] = f2bf(wfa0.z); dstA0[3] = f2bf(wfa0.w);                         \
        u16* dstA1 = &At[kkr1 * 32 + sc1];                                        \
        dstA1[0] = f2bf(wfa1.x); dstA1[1] = f2bf(wfa1.y);                         \
        dstA1[2] = f2bf(wfa1.z); dstA1[3] = f2bf(wfa1.w);                         \
        unsigned p0 = (unsigned)f2bf(xf0.x) | ((unsigned)f2bf(xf1.x) << 16);      \
        unsigned p1 = (unsigned)f2bf(xf0.y) | ((unsigned)f2bf(xf1.y) << 16);      \
        unsigned p2 = (unsigned)f2bf(xf0.z) | ((unsigned)f2bf(xf1.z) << 16);      \
        unsigned p3 = (unsigned)f2bf(xf0.w) | ((unsigned)f2bf(xf1.w) << 16);      \
        *(unsigned*)&Bt[(dq + 0) * 40 + colB] = p0;                               \
        *(unsigned*)&Bt[(dq + 1) * 40 + colB] = p1;                               \
        *(unsigned*)&Bt[(dq + 2) * 40 + colB] = p2;                               \
        *(unsigned*)&Bt[(dq + 3) * 40 + colB] = p3;                               \
    } while (0)

        f32x4 acc[4];
        #pragma unroll
        for (int fm = 0; fm < 4; ++fm) acc[fm] = (f32x4){0.f, 0.f, 0.f, 0.f};
        DLOAD(0);
        for (int t = 0; t < 16; ++t) {
            __syncthreads();                 // buffer free (reads of t-1 done)
            DWRITE();                        // write step t (vmcnt wait here)
            if (t < 15) DLOAD((t + 1) << 5); // issue next; wait lands next iter
            __syncthreads();                 // writes visible
            s16x8 af[4], bfr;
            #pragma unroll
            for (int fm = 0; fm < 4; ++fm)
                af[fm] = *(const s16x8*)&At[(fm * 16 + l16) * 32 + k8 * 8];
            bfr = *(const s16x8*)&Bt[((w << 4) + l16) * 40 + ((k8 ^ (l16 >> 2)) << 3)];
            #pragma unroll
            for (int fm = 0; fm < 4; ++fm)
                acc[fm] = __builtin_amdgcn_mfma_f32_16x16x32_bf16(af[fm], bfr, acc[fm], 0, 0, 0);
        }
#undef DLOAD
#undef DWRITE
        #pragma unroll
        for (int fm = 0; fm < 4; ++fm)
            #pragma unroll
            for (int j = 0; j < 4; ++j) {
                int r = fm * 16 + k8 * 4 + j;
                int c = (w << 4) + l16;
                outp[((size_t)(b * 64 + r)) * 2048 + d0 + c] = f2bf(acc[fm][j]);
            }
    } else if (bid < 5120) {
        // ---------------- weight transpose + cast 64x64 ----------------
        u16* tl = (u16*)smem;            // [64][68]
        int wb = bid - 2048;
        int which = wb >> 10;
        int t = wb & 1023;
        const float* in = which == 0 ? w0 : which == 1 ? w1 : w2;
        u16* out        = which == 0 ? o0 : which == 1 ? o1 : o2;
        int bx = (t & 31) * 64, by = (t >> 5) * 64;
        int tx = tid & 63, ty = tid >> 6;
        #pragma unroll 4
        for (int i = ty; i < 64; i += 4)
            tl[tx * 68 + i] = f2bf(in[(size_t)(by + i) * 2048 + bx + tx]);
        __syncthreads();
        int srow = tid >> 2, sq = tid & 3;
        const u16* lp = &tl[srow * 68 + sq * 16];
        u16* op = &out[(size_t)(bx + srow) * 2048 + by + sq * 16];
        #pragma unroll
        for (int j8 = 0; j8 < 4; ++j8)
            *(short4*)(op + j8 * 4) = *(const short4*)(lp + j8 * 4);
    } else {
        // ---------------- q cast ----------------
        int cb = bid - 5120;
        size_t base = (size_t)cb * 256 + tid;
        #pragma unroll
        for (int it = 0; it < 8; ++it) {
            size_t i = base + (size_t)it * 1048576;
            float4 f = ((const float4*)q)[i];
            ushort4 o;
            o.x = f2bf(f.x); o.y = f2bf(f.y); o.z = f2bf(f.z); o.w = f2bf(f.w);
            ((ushort4*)qb)[i] = o;
        }
    }
}

// ---------------------------------------------------------------------------
// 128x128 bf16 GEMM, dual: z=0: phik=elu(kds@wkT)+1; z=1: vals=vds@wvT
// ---------------------------------------------------------------------------
__global__ __launch_bounds__(256) void gemm128_dual(
    const u16* __restrict__ A0, const u16* __restrict__ B0, u16* __restrict__ C0,
    const u16* __restrict__ A1, const u16* __restrict__ B1, u16* __restrict__ C1)
{
    const u16* A  = blockIdx.z ? A1 : A0;
    const u16* BT = blockIdx.z ? B1 : B0;
    u16* C        = blockIdx.z ? C1 : C0;
    const bool elu = (blockIdx.z == 0);
    const int K = 2048;

    __shared__ __align__(16) u16 lds[2][8192];
    const int tid = threadIdx.x;
    const int w = tid >> 6, l = tid & 63;
    const int wm = w >> 1, wn = w & 1;
    const int l16 = l & 15, k8 = l >> 4;
    const int sr = (w << 4) + (l >> 2);
    const int sc = (l & 3) << 3;
    const int row0 = blockIdx.y * 128, col0 = blockIdx.x * 128;
    const int nk = K >> 5;
    f32x4 acc[4][4] = {};

#define STAGE(buf, kt) do {                                                        \
        int kk0 = (kt) << 5;                                                       \
        _Pragma("unroll")                                                          \
        for (int i = 0; i < 2; ++i) {                                              \
            const u16* ga = A + (size_t)(row0 + i * 64 + sr) * K + kk0 + sc;       \
            async16(&lds[buf][i * 2048 + (w << 9)], ga);                           \
            const u16* gb = BT + (size_t)(col0 + i * 64 + sr) * K + kk0 + sc;      \
            async16(&lds[buf][4096 + i * 2048 + (w << 9)], gb);                    \
        }                                                                          \
    } while (0)

    STAGE(0, 0);
    asm volatile("s_waitcnt vmcnt(0)" ::: "memory");
    __syncthreads();
    int cur = 0;
    for (int kt = 0; kt < nk; ++kt) {
        if (kt + 1 < nk) STAGE(cur ^ 1, kt + 1);
        s16x8 af[4], bfr[4];
        const u16* Ab = &lds[cur][0];
        const u16* Bb = &lds[cur][4096];
        #pragma unroll
        for (int fm = 0; fm < 4; ++fm)
            af[fm] = *(const s16x8*)&Ab[((wm << 6) + (fm << 4) + l16) * 32 + (k8 << 3)];
        #pragma unroll
        for (int fn = 0; fn < 4; ++fn)
            bfr[fn] = *(const s16x8*)&Bb[((wn << 6) + (fn << 4) + l16) * 32 + (k8 << 3)];
        #pragma unroll
        for (int fm = 0; fm < 4; ++fm)
            #pragma unroll
            for (int fn = 0; fn < 4; ++fn)
                acc[fm][fn] = __builtin_amdgcn_mfma_f32_16x16x32_bf16(af[fm], bfr[fn], acc[fm][fn], 0, 0, 0);
        __syncthreads();
        cur ^= 1;
    }
#undef STAGE

    #pragma unroll
    for (int fm = 0; fm < 4; ++fm)
        #pragma unroll
        for (int j = 0; j < 4; ++j) {
            int r = row0 + (wm << 6) + (fm << 4) + (k8 << 2) + j;
            size_t rbase = (size_t)r * 2048;
            #pragma unroll
            for (int fn = 0; fn < 4; ++fn) {
                int c = col0 + (wn << 6) + (fn << 4) + l16;
                float x = acc[fm][fn][j];
                if (elu) x = x > 0.0f ? x + 1.0f : __expf(x);
                C[rbase + c] = f2bf(x);
            }
        }
}

// ---------------------------------------------------------------------------
// s & z per (b,n): sT bf16 [B,N,128,128], z fp32 [B,N,128]  (R8-verified)
// ---------------------------------------------------------------------------
__global__ __launch_bounds__(256) void sz_kernel(
    const u16* __restrict__ phik, const u16* __restrict__ vals,
    u16* __restrict__ sT, float* __restrict__ z)
{
    int b = blockIdx.x >> 4, n = blockIdx.x & 15;
    __shared__ __align__(16) u16 pk[64 * 128];
    __shared__ __align__(16) u16 vv[64 * 128];
    int tid = threadIdx.x;
    for (int i = tid; i < 1024; i += 256) {
        int r = i >> 4, c8 = (i & 15) << 3;
        size_t g = ((size_t)(b * 64 + r)) * 2048 + n * 128 + c8;
        ((s16x8*)pk)[i] = *(const s16x8*)&phik[g];
        ((s16x8*)vv)[i] = *(const s16x8*)&vals[g];
    }
    __syncthreads();
    if (tid < 128) {
        float s = 0.0f;
        for (int kk = 0; kk < 64; ++kk) s += bf2f(pk[kk * 128 + tid]);
        z[((size_t)(b * 16 + n)) * 128 + tid] = s;
    }
    int hg = tid >> 4, dg = tid & 15;
    int h0 = hg * 8, d0 = dg * 8;
    float acc[8][8] = {};
    for (int kk = 0; kk < 64; ++kk) {
        s16x8 vr = *(const s16x8*)&vv[kk * 128 + h0];
        s16x8 pr = *(const s16x8*)&pk[kk * 128 + d0];
        float va[8], pa[8];
        #pragma unroll
        for (int i = 0; i < 8; ++i) { va[i] = bf2f((u16)vr[i]); pa[i] = bf2f((u16)pr[i]); }
        #pragma unroll
        for (int i = 0; i < 8; ++i)
            #pragma unroll
            for (int j = 0; j < 8; ++j)
                acc[i][j] += va[i] * pa[j];
    }
    size_t base = ((size_t)(b * 16 + n)) * 16384;
    #pragma unroll
    for (int i = 0; i < 8; ++i) {
        u16 row[8];
        #pragma unroll
        for (int j = 0; j < 8; ++j) row[j] = f2bf(acc[i][j]);
        *(s16x8*)&sT[base + (size_t)(h0 + i) * 128 + d0] = *(s16x8*)row;
    }
}

// ---------------------------------------------------------------------------
// gemm256_qs: 256x256 8-phase bf16 GEMM (phi_q) with FUSED qs epilogue v2.
// (R14-verified: P-half + sT tile staged in LDS, qz via broadcast-z MFMA.)
// ---------------------------------------------------------------------------
__global__ __launch_bounds__(512, 2) void gemm256_qs(
    const u16* __restrict__ A, const u16* __restrict__ BT,
    const u16* __restrict__ sT, const float* __restrict__ z,
    float* __restrict__ outp)
{
    const int K = 2048, NT = 32, nbn = 8;
    __shared__ __align__(16) u16 lds[8][8192];
    const int tid = threadIdx.x;
    const int w = tid >> 6, l = tid & 63;
    const int wm = w >> 2, wn = w & 3;
    const int l16 = l & 15, k8 = l >> 4;

    const int nwg = gridDim.x;
    int wg = blockIdx.x;
    if ((nwg & 7) == 0) wg = (wg & 7) * (nwg >> 3) + (wg >> 3);
    const int row0 = (wg / nbn) << 8, col0 = (wg % nbn) << 8;

    const int lr  = l >> 3;
    const int scb = (((l & 7) ^ lr) << 4);
    const int swzr = (l16 & 7) << 4;

#define PANEL(s, m, h) (&lds[((s) << 2) | ((m) << 1) | (h)][0])

#define STG(pan, G, prow0, kk0) do {                                             \
        _Pragma("unroll")                                                        \
        for (int i_ = 0; i_ < 2; ++i_) {                                         \
            int seg_ = w + (i_ << 3);                                            \
            const u16* src_ = (G) + (size_t)((prow0) + (seg_ << 3) + lr) * K     \
                              + (kk0) + (scb >> 1);                              \
            async16((pan) + (seg_ << 9), src_);                                  \
        } } while (0)

#define LDA(slot, mh) do { const u16* p_ = PANEL(slot, 0, mh);                   \
        _Pragma("unroll")                                                        \
        for (int fm_ = 0; fm_ < 4; ++fm_)                                        \
        _Pragma("unroll")                                                        \
        for (int ks_ = 0; ks_ < 2; ++ks_)                                        \
            Af[fm_][ks_] = *(const s16x8*)(p_ + (wm * 64 + fm_ * 16 + l16) * 64  \
                           + (((ks_ * 64 + k8 * 16) ^ swzr) >> 1)); } while (0)

#define LDB(slot, nh, dst) do { const u16* p_ = PANEL(slot, 1, nh);              \
        _Pragma("unroll")                                                        \
        for (int fn_ = 0; fn_ < 2; ++fn_)                                        \
        _Pragma("unroll")                                                        \
        for (int ks_ = 0; ks_ < 2; ++ks_)                                        \
            dst[fn_][ks_] = *(const s16x8*)(p_ + (wn * 32 + fn_ * 16 + l16) * 64 \
                           + (((ks_ * 64 + k8 * 16) ^ swzr) >> 1)); } while (0)

#define MM(mh, nh, BF) do {                                                      \
        __builtin_amdgcn_s_setprio(1);                                           \
        _Pragma("unroll")                                                        \
        for (int fm_ = 0; fm_ < 4; ++fm_)                                        \
        _Pragma("unroll")                                                        \
        for (int fn_ = 0; fn_ < 2; ++fn_)                                        \
        _Pragma("unroll")                                                        \
        for (int ks_ = 0; ks_ < 2; ++ks_)                                        \
            acc[mh][nh][fm_][fn_] = __builtin_amdgcn_mfma_f32_16x16x32_bf16(     \
                Af[fm_][ks_], BF[fn_][ks_], acc[mh][nh][fm_][fn_], 0, 0, 0);     \
        __builtin_amdgcn_s_setprio(0); } while (0)

#define TILE(t, cur, nxt, BFc, BFn) do {                                         \
        LDA(cur, 0);                                                             \
        if ((t) + 1 < NT) STG(PANEL(nxt, 0, 1), A, row0 + 128, ((t) + 1) << 6);  \
        BARRIER(); MM(0, 0, BFc); BARRIER();                                     \
        LDB(cur, 1, Bf1);                                                        \
        if ((t) + 2 < NT) STG(PANEL(cur, 0, 0), A, row0, ((t) + 2) << 6);        \
        BARRIER(); MM(0, 1, Bf1); BARRIER();                                     \
        LDA(cur, 1);                                                             \
        if ((t) + 2 < NT) STG(PANEL(cur, 1, 0), BT, col0, ((t) + 2) << 6);       \
        BARRIER(); MM(1, 1, Bf1); BARRIER();                                     \
        if ((t) + 2 < NT) STG(PANEL(cur, 1, 1), BT, col0 + 128, ((t) + 2) << 6); \
        BARRIER(); MM(1, 0, BFc);                                                \
        if ((t) == NT - 2)     asm volatile("s_waitcnt vmcnt(0)" ::: "memory");  \
        else if ((t) < NT - 2) asm volatile("s_waitcnt vmcnt(6)" ::: "memory");  \
        BARRIER();                                                               \
        if ((t) + 1 < NT) LDB(nxt, 0, BFn);                                      \
    } while (0)

    f32x4 acc[2][2][4][2] = {};
    s16x8 Af[4][2], Bf0a[2][2], Bf0b[2][2], Bf1[2][2];

    STG(PANEL(0, 0, 0), A,  row0,       0);
    STG(PANEL(0, 1, 0), BT, col0,       0);
    STG(PANEL(0, 1, 1), BT, col0 + 128, 0);
    STG(PANEL(0, 0, 1), A,  row0 + 128, 0);
    STG(PANEL(1, 0, 0), A,  row0,       64);
    STG(PANEL(1, 1, 0), BT, col0,       64);
    STG(PANEL(1, 1, 1), BT, col0 + 128, 64);
    asm volatile("s_waitcnt vmcnt(6)" ::: "memory");
    BARRIER();
    LDB(0, 0, Bf0a);

    for (int t = 0; t < NT; t += 2) {
        TILE(t,     0, 1, Bf0a, Bf0b);
        TILE(t + 1, 1, 0, Bf0b, Bf0a);
    }
#undef PANEL
#undef STG
#undef LDA
#undef LDB
#undef MM
#undef TILE

    // ---- fused qs epilogue v2 ----
    const int b = row0 >> 9;
    const int n0 = col0 >> 7;
    u16* Ph  = &lds[0][0];              // [256][128] swizzled P half
    u16* sTl = &lds[4][0];              // [128][128] swizzled sT tile

    #pragma unroll
    for (int nsel = 0; nsel < 2; ++nsel) {
        #pragma unroll
        for (int mh = 0; mh < 2; ++mh)
            #pragma unroll
            for (int fm = 0; fm < 4; ++fm)
                #pragma unroll
                for (int j = 0; j < 4; ++j) {
                    int rr = mh * 128 + wm * 64 + fm * 16 + k8 * 4 + j;
                    int rowbase = rr << 7;
                    int msk = ((rr >> 2) & 7) << 4;
                    #pragma unroll
                    for (int fn = 0; fn < 2; ++fn) {
                        int cc = wn * 32 + fn * 16 + l16;
                        float x = acc[mh][nsel][fm][fn][j];
                        x = x > 0.0f ? x + 1.0f : __expf(x);
                        Ph[rowbase + (cc ^ msk)] = f2bf(x);
                    }
                }
        {
            const size_t stb = ((size_t)(b * 16 + n0 + nsel)) << 14;
            #pragma unroll
            for (int it = 0; it < 4; ++it) {
                int g = (it << 12) + (tid << 3);
                int row = g >> 7;
                int ch8 = (g >> 3) & 15;
                const u16* src = sT + stb + (row << 7) + ((ch8 ^ (row & 7)) << 3);
                async16(&sTl[g], src);
            }
        }
        __syncthreads();

        const int nn = n0 + nsel;
        const float* zp0 = z + ((size_t)(b * 16 + nn) << 7);
        s16x8 Bz[4];
        #pragma unroll
        for (int ks = 0; ks < 4; ++ks) {
            const float* zp = zp0 + (ks << 5) + (k8 << 3);
            float4 f0 = *(const float4*)zp;
            float4 f1 = *(const float4*)(zp + 4);
            u16 tmp[8] = { f2bf(f0.x), f2bf(f0.y), f2bf(f0.z), f2bf(f0.w),
                           f2bf(f1.x), f2bf(f1.y), f2bf(f1.z), f2bf(f1.w) };
            Bz[ks] = *(const s16x8*)tmp;
        }

        s16x8 Af2[2][4];
        #pragma unroll
        for (int fm2 = 0; fm2 < 2; ++fm2) {
            int rr = (w << 5) + (fm2 << 4) + l16;
            int rowbase = rr << 7;
            int msk = ((rr >> 2) & 7) << 4;
            #pragma unroll
            for (int ks = 0; ks < 4; ++ks) {
                int cc = (ks << 5) + (k8 << 3);
                Af2[fm2][ks] = *(const s16x8*)&Ph[rowbase + (cc ^ msk)];
            }
        }

        f32x4 accz[2] = {};
        #pragma unroll
        for (int fm2 = 0; fm2 < 2; ++fm2)
            #pragma unroll
            for (int ks = 0; ks < 4; ++ks)
                accz[fm2] = __builtin_amdgcn_mfma_f32_16x16x32_bf16(Af2[fm2][ks], Bz[ks], accz[fm2], 0, 0, 0);

        f32x4 acc2[2][8] = {};
        #pragma unroll
        for (int fn = 0; fn < 8; ++fn) {
            s16x8 Bfr[4];
            #pragma unroll
            for (int ks = 0; ks < 4; ++ks) {
                int rw = (fn << 4) + l16;
                Bfr[ks] = *(const s16x8*)&sTl[(rw << 7)
                            + (((ks << 5) + (k8 << 3)) ^ ((rw & 7) << 3))];
            }
            #pragma unroll
            for (int fm2 = 0; fm2 < 2; ++fm2)
                #pragma unroll
                for (int ks = 0; ks < 4; ++ks)
                    acc2[fm2][fn] = __builtin_amdgcn_mfma_f32_16x16x32_bf16(Af2[fm2][ks], Bfr[ks], acc2[fm2][fn], 0, 0, 0);
        }

        #pragma unroll
        for (int fm2 = 0; fm2 < 2; ++fm2)
            #pragma unroll
            for (int j = 0; j < 4; ++j) {
                int grow = row0 + (w << 5) + (fm2 << 4) + (k8 << 2) + j;
                float rq = 1.0f / (accz[fm2][j] + EPS);
                size_t ob = (size_t)grow * 2048 + col0 + (nsel << 7);
                #pragma unroll
                for (int fn = 0; fn < 8; ++fn)
                    outp[ob + (fn << 4) + l16] = acc2[fm2][fn][j] * rq;
            }
        __syncthreads();
    }
}

// ---------------------------------------------------------------------------
extern "C" void kernel_launch(void* const* d_in, const int* in_sizes, int n_in,
                              void* d_out, int out_size, void* d_ws, size_t ws_size,
                              hipStream_t stream) {
    (void)in_sizes; (void)n_in; (void)out_size; (void)ws_size;
    const float* q   = (const float*)d_in[0];
    const float* k   = (const float*)d_in[1];
    const float* v   = (const float*)d_in[2];
    const float* wq  = (const float*)d_in[3];
    const float* wk  = (const float*)d_in[4];
    const float* wv  = (const float*)d_in[5];
    const float* kdw = (const float*)d_in[6];
    const float* vdw = (const float*)d_in[7];
    float* out = (float*)d_out;

    char* p = (char*)d_ws;
    u16* qb   = (u16*)p; p += (size_t)16384 * 2048 * 2;
    u16* wqT  = (u16*)p; p += (size_t)2048 * 2048 * 2;
    u16* wkT  = (u16*)p; p += (size_t)2048 * 2048 * 2;
    u16* wvT  = (u16*)p; p += (size_t)2048 * 2048 * 2;
    u16* kds  = (u16*)p; p += (size_t)2048 * 2048 * 2;
    u16* vds  = (u16*)p; p += (size_t)2048 * 2048 * 2;
    u16* phik = (u16*)p; p += (size_t)2048 * 2048 * 2;
    u16* vals = (u16*)p; p += (size_t)2048 * 2048 * 2;
    u16* sT   = (u16*)p; p += (size_t)512 * 128 * 128 * 2;
    float* z  = (float*)p; p += (size_t)512 * 128 * 4;

    prep_down<<<9216, 256, 0, stream>>>(q, qb, wq, wk, wv, wqT, wkT, wvT,
                                        k, v, kdw, vdw, kds, vds);
    gemm128_dual<<<dim3(16, 16, 2), 256, 0, stream>>>(kds, wkT, phik, vds, wvT, vals);
    sz_kernel<<<512, 256, 0, stream>>>(phik, vals, sT, z);
    gemm256_qs<<<512, 512, 0, stream>>>(qb, wqT, sT, z, out);
}

// Round 17
// 344.499 us; speedup vs baseline: 1.0305x; 1.0076x over previous
//
#include <hip/hip_runtime.h>
#include <cstdint>
#include <cstddef>

typedef float f32x4 __attribute__((ext_vector_type(4)));
typedef short s16x8 __attribute__((ext_vector_type(8)));
typedef unsigned short u16;

#define EPS 1e-6f

__device__ __forceinline__ u16 f2bf(float f) {
    unsigned u = __float_as_uint(f);
    u += 0x7FFFu + ((u >> 16) & 1u);
    return (u16)(u >> 16);
}
__device__ __forceinline__ float bf2f(u16 u) {
    return __uint_as_float(((unsigned)u) << 16);
}

typedef const __attribute__((address_space(1))) void cg_void;
typedef __attribute__((address_space(3))) void l_void;
__device__ __forceinline__ void async16(void* dst_lds, const void* src_g) {
    __builtin_amdgcn_global_load_lds((cg_void*)src_g, (l_void*)dst_lds, 16, 0, 0);
}

#define BARRIER() do { asm volatile("" ::: "memory"); \
                       __builtin_amdgcn_s_barrier();  \
                       asm volatile("" ::: "memory"); } while (0)

// ---------------------------------------------------------------------------
// prep_down: all preprocessing in one launch (9216 blocks) — R14-verified
// best config (graph-total A/B: merged 344.9 vs split 355.0). T14 prefetch
// REMOVED (R16: neutral — latency hidden was repaid by occupancy 78->58%).
//   [0,2048):     downsample via MFMA (64-col d-slices, XOR-swz Bt, 1-buf)
//   [2048,5120):  weight transpose+cast 64x64 tiles
//   [5120,9216):  q cast fp32->bf16
// ---------------------------------------------------------------------------
__global__ __launch_bounds__(256) void prep_down(
    const float* __restrict__ q, u16* __restrict__ qb,
    const float* __restrict__ w0, const float* __restrict__ w1,
    const float* __restrict__ w2, u16* __restrict__ o0,
    u16* __restrict__ o1, u16* __restrict__ o2,
    const float* __restrict__ kin, const float* __restrict__ vin,
    const float* __restrict__ wdk, const float* __restrict__ wdv,
    u16* __restrict__ kds, u16* __restrict__ vds)
{
    __shared__ __align__(16) char smem[9216];
    const int bid = blockIdx.x;
    const int tid = threadIdx.x;

    if (bid < 2048) {
        // ---------------- downsample via MFMA ----------------
        u16* At = (u16*)smem;            // [64][32]
        u16* Bt = (u16*)(smem + 4096);   // [64][40] XOR-swizzled
        const int sel = bid >> 10, rem = bid & 1023;
        const int b = rem >> 5, d0 = (rem & 31) << 6;
        const float* x  = sel ? vin : kin;
        const float* wd = sel ? wdv : wdk;
        u16* outp       = sel ? vds : kds;
        const int w = tid >> 6, l = tid & 63, l16 = l & 15, k8 = l >> 4;
        f32x4 acc[4];
        #pragma unroll
        for (int fm = 0; fm < 4; ++fm) acc[fm] = (f32x4){0.f, 0.f, 0.f, 0.f};
        for (int s0 = 0; s0 < 512; s0 += 32) {
            __syncthreads();
            for (int c = tid; c < 512; c += 256) {
                int kkr = c >> 3, sc = (c & 7) << 2;
                float4 f = *(const float4*)&wd[kkr * 512 + s0 + sc];
                u16* dst = &At[kkr * 32 + sc];
                dst[0] = f2bf(f.x); dst[1] = f2bf(f.y); dst[2] = f2bf(f.z); dst[3] = f2bf(f.w);
            }
            {
                int c = tid;
                int sp = c >> 4, dq = (c & 15) << 2;
                int srow = sp << 1;
                const float* xp = &x[((size_t)(b * 512) + s0 + srow) * 2048 + d0 + dq];
                float4 f0 = *(const float4*)xp;
                float4 f1 = *(const float4*)(xp + 2048);
                int col = srow ^ ((c & 3) << 3);
                unsigned p0 = (unsigned)f2bf(f0.x) | ((unsigned)f2bf(f1.x) << 16);
                unsigned p1 = (unsigned)f2bf(f0.y) | ((unsigned)f2bf(f1.y) << 16);
                unsigned p2 = (unsigned)f2bf(f0.z) | ((unsigned)f2bf(f1.z) << 16);
                unsigned p3 = (unsigned)f2bf(f0.w) | ((unsigned)f2bf(f1.w) << 16);
                *(unsigned*)&Bt[(dq + 0) * 40 + col] = p0;
                *(unsigned*)&Bt[(dq + 1) * 40 + col] = p1;
                *(unsigned*)&Bt[(dq + 2) * 40 + col] = p2;
                *(unsigned*)&Bt[(dq + 3) * 40 + col] = p3;
            }
            __syncthreads();
            s16x8 af[4], bfr;
            #pragma unroll
            for (int fm = 0; fm < 4; ++fm)
                af[fm] = *(const s16x8*)&At[(fm * 16 + l16) * 32 + k8 * 8];
            bfr = *(const s16x8*)&Bt[((w << 4) + l16) * 40 + ((k8 ^ (l16 >> 2)) << 3)];
            #pragma unroll
            for (int fm = 0; fm < 4; ++fm)
                acc[fm] = __builtin_amdgcn_mfma_f32_16x16x32_bf16(af[fm], bfr, acc[fm], 0, 0, 0);
        }
        #pragma unroll
        for (int fm = 0; fm < 4; ++fm)
            #pragma unroll
            for (int j = 0; j < 4; ++j) {
                int r = fm * 16 + k8 * 4 + j;
                int c = (w << 4) + l16;
                outp[((size_t)(b * 64 + r)) * 2048 + d0 + c] = f2bf(acc[fm][j]);
            }
    } else if (bid < 5120) {
        // ---------------- weight transpose + cast 64x64 ----------------
        u16* tl = (u16*)smem;            // [64][68]
        int wb = bid - 2048;
        int which = wb >> 10;
        int t = wb & 1023;
        const float* in = which == 0 ? w0 : which == 1 ? w1 : w2;
        u16* out        = which == 0 ? o0 : which == 1 ? o1 : o2;
        int bx = (t & 31) * 64, by = (t >> 5) * 64;
        int tx = tid & 63, ty = tid >> 6;
        #pragma unroll 4
        for (int i = ty; i < 64; i += 4)
            tl[tx * 68 + i] = f2bf(in[(size_t)(by + i) * 2048 + bx + tx]);
        __syncthreads();
        int srow = tid >> 2, sq = tid & 3;
        const u16* lp = &tl[srow * 68 + sq * 16];
        u16* op = &out[(size_t)(bx + srow) * 2048 + by + sq * 16];
        #pragma unroll
        for (int j8 = 0; j8 < 4; ++j8)
            *(short4*)(op + j8 * 4) = *(const short4*)(lp + j8 * 4);
    } else {
        // ---------------- q cast ----------------
        int cb = bid - 5120;
        size_t base = (size_t)cb * 256 + tid;
        #pragma unroll
        for (int it = 0; it < 8; ++it) {
            size_t i = base + (size_t)it * 1048576;
            float4 f = ((const float4*)q)[i];
            ushort4 o;
            o.x = f2bf(f.x); o.y = f2bf(f.y); o.z = f2bf(f.z); o.w = f2bf(f.w);
            ((ushort4*)qb)[i] = o;
        }
    }
}

// ---------------------------------------------------------------------------
// 128x128 bf16 GEMM, dual: z=0: phik=elu(kds@wkT)+1; z=1: vals=vds@wvT
// ---------------------------------------------------------------------------
__global__ __launch_bounds__(256) void gemm128_dual(
    const u16* __restrict__ A0, const u16* __restrict__ B0, u16* __restrict__ C0,
    const u16* __restrict__ A1, const u16* __restrict__ B1, u16* __restrict__ C1)
{
    const u16* A  = blockIdx.z ? A1 : A0;
    const u16* BT = blockIdx.z ? B1 : B0;
    u16* C        = blockIdx.z ? C1 : C0;
    const bool elu = (blockIdx.z == 0);
    const int K = 2048;

    __shared__ __align__(16) u16 lds[2][8192];
    const int tid = threadIdx.x;
    const int w = tid >> 6, l = tid & 63;
    const int wm = w >> 1, wn = w & 1;
    const int l16 = l & 15, k8 = l >> 4;
    const int sr = (w << 4) + (l >> 2);
    const int sc = (l & 3) << 3;
    const int row0 = blockIdx.y * 128, col0 = blockIdx.x * 128;
    const int nk = K >> 5;
    f32x4 acc[4][4] = {};

#define STAGE(buf, kt) do {                                                        \
        int kk0 = (kt) << 5;                                                       \
        _Pragma("unroll")                                                          \
        for (int i = 0; i < 2; ++i) {                                              \
            const u16* ga = A + (size_t)(row0 + i * 64 + sr) * K + kk0 + sc;       \
            async16(&lds[buf][i * 2048 + (w << 9)], ga);                           \
            const u16* gb = BT + (size_t)(col0 + i * 64 + sr) * K + kk0 + sc;      \
            async16(&lds[buf][4096 + i * 2048 + (w << 9)], gb);                    \
        }                                                                          \
    } while (0)

    STAGE(0, 0);
    asm volatile("s_waitcnt vmcnt(0)" ::: "memory");
    __syncthreads();
    int cur = 0;
    for (int kt = 0; kt < nk; ++kt) {
        if (kt + 1 < nk) STAGE(cur ^ 1, kt + 1);
        s16x8 af[4], bfr[4];
        const u16* Ab = &lds[cur][0];
        const u16* Bb = &lds[cur][4096];
        #pragma unroll
        for (int fm = 0; fm < 4; ++fm)
            af[fm] = *(const s16x8*)&Ab[((wm << 6) + (fm << 4) + l16) * 32 + (k8 << 3)];
        #pragma unroll
        for (int fn = 0; fn < 4; ++fn)
            bfr[fn] = *(const s16x8*)&Bb[((wn << 6) + (fn << 4) + l16) * 32 + (k8 << 3)];
        #pragma unroll
        for (int fm = 0; fm < 4; ++fm)
            #pragma unroll
            for (int fn = 0; fn < 4; ++fn)
                acc[fm][fn] = __builtin_amdgcn_mfma_f32_16x16x32_bf16(af[fm], bfr[fn], acc[fm][fn], 0, 0, 0);
        __syncthreads();
        cur ^= 1;
    }
#undef STAGE

    #pragma unroll
    for (int fm = 0; fm < 4; ++fm)
        #pragma unroll
        for (int j = 0; j < 4; ++j) {
            int r = row0 + (wm << 6) + (fm << 4) + (k8 << 2) + j;
            size_t rbase = (size_t)r * 2048;
            #pragma unroll
            for (int fn = 0; fn < 4; ++fn) {
                int c = col0 + (wn << 6) + (fn << 4) + l16;
                float x = acc[fm][fn][j];
                if (elu) x = x > 0.0f ? x + 1.0f : __expf(x);
                C[rbase + c] = f2bf(x);
            }
        }
}

// ---------------------------------------------------------------------------
// s & z per (b,n): sT bf16 [B,N,128,128], z fp32 [B,N,128]  (R8-verified)
// ---------------------------------------------------------------------------
__global__ __launch_bounds__(256) void sz_kernel(
    const u16* __restrict__ phik, const u16* __restrict__ vals,
    u16* __restrict__ sT, float* __restrict__ z)
{
    int b = blockIdx.x >> 4, n = blockIdx.x & 15;
    __shared__ __align__(16) u16 pk[64 * 128];
    __shared__ __align__(16) u16 vv[64 * 128];
    int tid = threadIdx.x;
    for (int i = tid; i < 1024; i += 256) {
        int r = i >> 4, c8 = (i & 15) << 3;
        size_t g = ((size_t)(b * 64 + r)) * 2048 + n * 128 + c8;
        ((s16x8*)pk)[i] = *(const s16x8*)&phik[g];
        ((s16x8*)vv)[i] = *(const s16x8*)&vals[g];
    }
    __syncthreads();
    if (tid < 128) {
        float s = 0.0f;
        for (int kk = 0; kk < 64; ++kk) s += bf2f(pk[kk * 128 + tid]);
        z[((size_t)(b * 16 + n)) * 128 + tid] = s;
    }
    int hg = tid >> 4, dg = tid & 15;
    int h0 = hg * 8, d0 = dg * 8;
    float acc[8][8] = {};
    for (int kk = 0; kk < 64; ++kk) {
        s16x8 vr = *(const s16x8*)&vv[kk * 128 + h0];
        s16x8 pr = *(const s16x8*)&pk[kk * 128 + d0];
        float va[8], pa[8];
        #pragma unroll
        for (int i = 0; i < 8; ++i) { va[i] = bf2f((u16)vr[i]); pa[i] = bf2f((u16)pr[i]); }
        #pragma unroll
        for (int i = 0; i < 8; ++i)
            #pragma unroll
            for (int j = 0; j < 8; ++j)
                acc[i][j] += va[i] * pa[j];
    }
    size_t base = ((size_t)(b * 16 + n)) * 16384;
    #pragma unroll
    for (int i = 0; i < 8; ++i) {
        u16 row[8];
        #pragma unroll
        for (int j = 0; j < 8; ++j) row[j] = f2bf(acc[i][j]);
        *(s16x8*)&sT[base + (size_t)(h0 + i) * 128 + d0] = *(s16x8*)row;
    }
}

// ---------------------------------------------------------------------------
// gemm256_qs: 256x256 8-phase bf16 GEMM (phi_q) with FUSED qs epilogue v2.
// (R14-verified: P-half + sT tile staged in LDS, qz via broadcast-z MFMA.)
// ---------------------------------------------------------------------------
__global__ __launch_bounds__(512, 2) void gemm256_qs(
    const u16* __restrict__ A, const u16* __restrict__ BT,
    const u16* __restrict__ sT, const float* __restrict__ z,
    float* __restrict__ outp)
{
    const int K = 2048, NT = 32, nbn = 8;
    __shared__ __align__(16) u16 lds[8][8192];
    const int tid = threadIdx.x;
    const int w = tid >> 6, l = tid & 63;
    const int wm = w >> 2, wn = w & 3;
    const int l16 = l & 15, k8 = l >> 4;

    const int nwg = gridDim.x;
    int wg = blockIdx.x;
    if ((nwg & 7) == 0) wg = (wg & 7) * (nwg >> 3) + (wg >> 3);
    const int row0 = (wg / nbn) << 8, col0 = (wg % nbn) << 8;

    const int lr  = l >> 3;
    const int scb = (((l & 7) ^ lr) << 4);
    const int swzr = (l16 & 7) << 4;

#define PANEL(s, m, h) (&lds[((s) << 2) | ((m) << 1) | (h)][0])

#define STG(pan, G, prow0, kk0) do {                                             \
        _Pragma("unroll")                                                        \
        for (int i_ = 0; i_ < 2; ++i_) {                                         \
            int seg_ = w + (i_ << 3);                                            \
            const u16* src_ = (G) + (size_t)((prow0) + (seg_ << 3) + lr) * K     \
                              + (kk0) + (scb >> 1);                              \
            async16((pan) + (seg_ << 9), src_);                                  \
        } } while (0)

#define LDA(slot, mh) do { const u16* p_ = PANEL(slot, 0, mh);                   \
        _Pragma("unroll")                                                        \
        for (int fm_ = 0; fm_ < 4; ++fm_)                                        \
        _Pragma("unroll")                                                        \
        for (int ks_ = 0; ks_ < 2; ++ks_)                                        \
            Af[fm_][ks_] = *(const s16x8*)(p_ + (wm * 64 + fm_ * 16 + l16) * 64  \
                           + (((ks_ * 64 + k8 * 16) ^ swzr) >> 1)); } while (0)

#define LDB(slot, nh, dst) do { const u16* p_ = PANEL(slot, 1, nh);              \
        _Pragma("unroll")                                                        \
        for (int fn_ = 0; fn_ < 2; ++fn_)                                        \
        _Pragma("unroll")                                                        \
        for (int ks_ = 0; ks_ < 2; ++ks_)                                        \
            dst[fn_][ks_] = *(const s16x8*)(p_ + (wn * 32 + fn_ * 16 + l16) * 64 \
                           + (((ks_ * 64 + k8 * 16) ^ swzr) >> 1)); } while (0)

#define MM(mh, nh, BF) do {                                                      \
        __builtin_amdgcn_s_setprio(1);                                           \
        _Pragma("unroll")                                                        \
        for (int fm_ = 0; fm_ < 4; ++fm_)                                        \
        _Pragma("unroll")                                                        \
        for (int fn_ = 0; fn_ < 2; ++fn_)                                        \
        _Pragma("unroll")                                                        \
        for (int ks_ = 0; ks_ < 2; ++ks_)                                        \
            acc[mh][nh][fm_][fn_] = __builtin_amdgcn_mfma_f32_16x16x32_bf16(     \
                Af[fm_][ks_], BF[fn_][ks_], acc[mh][nh][fm_][fn_], 0, 0, 0);     \
        __builtin_amdgcn_s_setprio(0); } while (0)

#define TILE(t, cur, nxt, BFc, BFn) do {                                         \
        LDA(cur, 0);                                                             \
        if ((t) + 1 < NT) STG(PANEL(nxt, 0, 1), A, row0 + 128, ((t) + 1) << 6);  \
        BARRIER(); MM(0, 0, BFc); BARRIER();                                     \
        LDB(cur, 1, Bf1);                                                        \
        if ((t) + 2 < NT) STG(PANEL(cur, 0, 0), A, row0, ((t) + 2) << 6);        \
        BARRIER(); MM(0, 1, Bf1); BARRIER();                                     \
        LDA(cur, 1);                                                             \
        if ((t) + 2 < NT) STG(PANEL(cur, 1, 0), BT, col0, ((t) + 2) << 6);       \
        BARRIER(); MM(1, 1, Bf1); BARRIER();                                     \
        if ((t) + 2 < NT) STG(PANEL(cur, 1, 1), BT, col0 + 128, ((t) + 2) << 6); \
        BARRIER(); MM(1, 0, BFc);                                                \
        if ((t) == NT - 2)     asm volatile("s_waitcnt vmcnt(0)" ::: "memory");  \
        else if ((t) < NT - 2) asm volatile("s_waitcnt vmcnt(6)" ::: "memory");  \
        BARRIER();                                                               \
        if ((t) + 1 < NT) LDB(nxt, 0, BFn);                                      \
    } while (0)

    f32x4 acc[2][2][4][2] = {};
    s16x8 Af[4][2], Bf0a[2][2], Bf0b[2][2], Bf1[2][2];

    STG(PANEL(0, 0, 0), A,  row0,       0);
    STG(PANEL(0, 1, 0), BT, col0,       0);
    STG(PANEL(0, 1, 1), BT, col0 + 128, 0);
    STG(PANEL(0, 0, 1), A,  row0 + 128, 0);
    STG(PANEL(1, 0, 0), A,  row0,       64);
    STG(PANEL(1, 1, 0), BT, col0,       64);
    STG(PANEL(1, 1, 1), BT, col0 + 128, 64);
    asm volatile("s_waitcnt vmcnt(6)" ::: "memory");
    BARRIER();
    LDB(0, 0, Bf0a);

    for (int t = 0; t < NT; t += 2) {
        TILE(t,     0, 1, Bf0a, Bf0b);
        TILE(t + 1, 1, 0, Bf0b, Bf0a);
    }
#undef PANEL
#undef STG
#undef LDA
#undef LDB
#undef MM
#undef TILE

    // ---- fused qs epilogue v2 ----
    const int b = row0 >> 9;
    const int n0 = col0 >> 7;
    u16* Ph  = &lds[0][0];              // [256][128] swizzled P half
    u16* sTl = &lds[4][0];              // [128][128] swizzled sT tile

    #pragma unroll
    for (int nsel = 0; nsel < 2; ++nsel) {
        #pragma unroll
        for (int mh = 0; mh < 2; ++mh)
            #pragma unroll
            for (int fm = 0; fm < 4; ++fm)
                #pragma unroll
                for (int j = 0; j < 4; ++j) {
                    int rr = mh * 128 + wm * 64 + fm * 16 + k8 * 4 + j;
                    int rowbase = rr << 7;
                    int msk = ((rr >> 2) & 7) << 4;
                    #pragma unroll
                    for (int fn = 0; fn < 2; ++fn) {
                        int cc = wn * 32 + fn * 16 + l16;
                        float x = acc[mh][nsel][fm][fn][j];
                        x = x > 0.0f ? x + 1.0f : __expf(x);
                        Ph[rowbase + (cc ^ msk)] = f2bf(x);
                    }
                }
        {
            const size_t stb = ((size_t)(b * 16 + n0 + nsel)) << 14;
            #pragma unroll
            for (int it = 0; it < 4; ++it) {
                int g = (it << 12) + (tid << 3);
                int row = g >> 7;
                int ch8 = (g >> 3) & 15;
                const u16* src = sT + stb + (row << 7) + ((ch8 ^ (row & 7)) << 3);
                async16(&sTl[g], src);
            }
        }
        __syncthreads();

        const int nn = n0 + nsel;
        const float* zp0 = z + ((size_t)(b * 16 + nn) << 7);
        s16x8 Bz[4];
        #pragma unroll
        for (int ks = 0; ks < 4; ++ks) {
            const float* zp = zp0 + (ks << 5) + (k8 << 3);
            float4 f0 = *(const float4*)zp;
            float4 f1 = *(const float4*)(zp + 4);
            u16 tmp[8] = { f2bf(f0.x), f2bf(f0.y), f2bf(f0.z), f2bf(f0.w),
                           f2bf(f1.x), f2bf(f1.y), f2bf(f1.z), f2bf(f1.w) };
            Bz[ks] = *(const s16x8*)tmp;
        }

        s16x8 Af2[2][4];
        #pragma unroll
        for (int fm2 = 0; fm2 < 2; ++fm2) {
            int rr = (w << 5) + (fm2 << 4) + l16;
            int rowbase = rr << 7;
            int msk = ((rr >> 2) & 7) << 4;
            #pragma unroll
            for (int ks = 0; ks < 4; ++ks) {
                int cc = (ks << 5) + (k8 << 3);
                Af2[fm2][ks] = *(const s16x8*)&Ph[rowbase + (cc ^ msk)];
            }
        }

        f32x4 accz[2] = {};
        #pragma unroll
        for (int fm2 = 0; fm2 < 2; ++fm2)
            #pragma unroll
            for (int ks = 0; ks < 4; ++ks)
                accz[fm2] = __builtin_amdgcn_mfma_f32_16x16x32_bf16(Af2[fm2][ks], Bz[ks], accz[fm2], 0, 0, 0);

        f32x4 acc2[2][8] = {};
        #pragma unroll
        for (int fn = 0; fn < 8; ++fn) {
            s16x8 Bfr[4];
            #pragma unroll
            for (int ks = 0; ks < 4; ++ks) {
                int rw = (fn << 4) + l16;
                Bfr[ks] = *(const s16x8*)&sTl[(rw << 7)
                            + (((ks << 5) + (k8 << 3)) ^ ((rw & 7) << 3))];
            }
            #pragma unroll
            for (int fm2 = 0; fm2 < 2; ++fm2)
                #pragma unroll
                for (int ks = 0; ks < 4; ++ks)
                    acc2[fm2][fn] = __builtin_amdgcn_mfma_f32_16x16x32_bf16(Af2[fm2][ks], Bfr[ks], acc2[fm2][fn], 0, 0, 0);
        }

        #pragma unroll
        for (int fm2 = 0; fm2 < 2; ++fm2)
            #pragma unroll
            for (int j = 0; j < 4; ++j) {
                int grow = row0 + (w << 5) + (fm2 << 4) + (k8 << 2) + j;
                float rq = 1.0f / (accz[fm2][j] + EPS);
                size_t ob = (size_t)grow * 2048 + col0 + (nsel << 7);
                #pragma unroll
                for (int fn = 0; fn < 8; ++fn)
                    outp[ob + (fn << 4) + l16] = acc2[fm2][fn][j] * rq;
            }
        __syncthreads();
    }
}

// ---------------------------------------------------------------------------
extern "C" void kernel_launch(void* const* d_in, const int* in_sizes, int n_in,
                              void* d_out, int out_size, void* d_ws, size_t ws_size,
                              hipStream_t stream) {
    (void)in_sizes; (void)n_in; (void)out_size; (void)ws_size;
    const float* q   = (const float*)d_in[0];
    const float* k   = (const float*)d_in[1];
    const float* v   = (const float*)d_in[2];
    const float* wq  = (const float*)d_in[3];
    const float* wk  = (const float*)d_in[4];
    const float* wv  = (const float*)d_in[5];
    const float* kdw = (const float*)d_in[6];
    const float* vdw = (const float*)d_in[7];
    float* out = (float*)d_out;

    char* p = (char*)d_ws;
    u16* qb   = (u16*)p; p += (size_t)16384 * 2048 * 2;
    u16* wqT  = (u16*)p; p += (size_t)2048 * 2048 * 2;
    u16* wkT  = (u16*)p; p += (size_t)2048 * 2048 * 2;
    u16* wvT  = (u16*)p; p += (size_t)2048 * 2048 * 2;
    u16* kds  = (u16*)p; p += (size_t)2048 * 2048 * 2;
    u16* vds  = (u16*)p; p += (size_t)2048 * 2048 * 2;
    u16* phik = (u16*)p; p += (size_t)2048 * 2048 * 2;
    u16* vals = (u16*)p; p += (size_t)2048 * 2048 * 2;
    u16* sT   = (u16*)p; p += (size_t)512 * 128 * 128 * 2;
    float* z  = (float*)p; p += (size_t)512 * 128 * 4;

    prep_down<<<9216, 256, 0, stream>>>(q, qb, wq, wk, wv, wqT, wkT, wvT,
                                        k, v, kdw, vdw, kds, vds);
    gemm128_dual<<<dim3(16, 16, 2), 256, 0, stream>>>(kds, wkT, phik, vds, wvT, vals);
    sz_kernel<<<512, 256, 0, stream>>>(phik, vals, sT, z);
    gemm256_qs<<<512, 512, 0, stream>>>(qb, wqT, sT, z, out);
}

// Round 18
// 342.130 us; speedup vs baseline: 1.0376x; 1.0069x over previous
//
#include <hip/hip_runtime.h>
#include <cstdint>
#include <cstddef>

typedef float f32x4 __attribute__((ext_vector_type(4)));
typedef short s16x8 __attribute__((ext_vector_type(8)));
typedef unsigned short u16;

#define EPS 1e-6f

__device__ __forceinline__ u16 f2bf(float f) {
    unsigned u = __float_as_uint(f);
    u += 0x7FFFu + ((u >> 16) & 1u);
    return (u16)(u >> 16);
}
__device__ __forceinline__ float bf2f(u16 u) {
    return __uint_as_float(((unsigned)u) << 16);
}

typedef const __attribute__((address_space(1))) void cg_void;
typedef __attribute__((address_space(3))) void l_void;
__device__ __forceinline__ void async16(void* dst_lds, const void* src_g) {
    __builtin_amdgcn_global_load_lds((cg_void*)src_g, (l_void*)dst_lds, 16, 0, 0);
}

#define BARRIER() do { asm volatile("" ::: "memory"); \
                       __builtin_amdgcn_s_barrier();  \
                       asm volatile("" ::: "memory"); } while (0)

// ---------------------------------------------------------------------------
// prep_down: all preprocessing in one launch (9216 blocks) — R14/R17 merge.
//   [0,2048):     downsample via MFMA. K-STEP 64 (8 iters, was 16): halves
//                 barriers, doubles loads-in-flight. At/Bt [64][72] pad-72:
//                 fixes latent 8-way At read conflict (stride 144B -> 2-way).
//                 LDS 18.4KB <= 20KB so occupancy stays 8 blocks/CU (wave cap).
//   [2048,5120):  weight transpose+cast 64x64 tiles
//   [5120,9216):  q cast fp32->bf16
// ---------------------------------------------------------------------------
__global__ __launch_bounds__(256) void prep_down(
    const float* __restrict__ q, u16* __restrict__ qb,
    const float* __restrict__ w0, const float* __restrict__ w1,
    const float* __restrict__ w2, u16* __restrict__ o0,
    u16* __restrict__ o1, u16* __restrict__ o2,
    const float* __restrict__ kin, const float* __restrict__ vin,
    const float* __restrict__ wdk, const float* __restrict__ wdv,
    u16* __restrict__ kds, u16* __restrict__ vds)
{
    __shared__ __align__(16) char smem[18432];
    const int bid = blockIdx.x;
    const int tid = threadIdx.x;

    if (bid < 2048) {
        // ---------------- downsample via MFMA (K-step 64) ----------------
        u16* At = (u16*)smem;            // [64][72]
        u16* Bt = (u16*)(smem + 9216);   // [64][72] XOR-swizzled per 32-chunk
        const int sel = bid >> 10, rem = bid & 1023;
        const int b = rem >> 5, d0 = (rem & 31) << 6;
        const float* x  = sel ? vin : kin;
        const float* wd = sel ? wdv : wdk;
        u16* outp       = sel ? vds : kds;
        const int w = tid >> 6, l = tid & 63, l16 = l & 15, k8 = l >> 4;
        f32x4 acc[4];
        #pragma unroll
        for (int fm = 0; fm < 4; ++fm) acc[fm] = (f32x4){0.f, 0.f, 0.f, 0.f};
        for (int s0 = 0; s0 < 512; s0 += 64) {
            __syncthreads();
            #pragma unroll
            for (int u = 0; u < 4; ++u) {            // A: 64 rows x 16 quads
                int c = tid + (u << 8);
                int kkr = c >> 4, sc = (c & 15) << 2;
                float4 f = *(const float4*)&wd[kkr * 512 + s0 + sc];
                u16* dst = &At[kkr * 72 + sc];
                dst[0] = f2bf(f.x); dst[1] = f2bf(f.y); dst[2] = f2bf(f.z); dst[3] = f2bf(f.w);
            }
            #pragma unroll
            for (int u = 0; u < 2; ++u) {            // B: 32 s-pairs x 16 d-quads
                int c = tid + (u << 8);
                int sp = c >> 4, dq = (c & 15) << 2;
                int srow = sp << 1;                  // 0..62
                const float* xp = &x[((size_t)(b * 512) + s0 + srow) * 2048 + d0 + dq];
                float4 f0 = *(const float4*)xp;
                float4 f1 = *(const float4*)(xp + 2048);
                int col = (srow & 32) | ((srow & 31) ^ ((c & 3) << 3));
                unsigned p0 = (unsigned)f2bf(f0.x) | ((unsigned)f2bf(f1.x) << 16);
                unsigned p1 = (unsigned)f2bf(f0.y) | ((unsigned)f2bf(f1.y) << 16);
                unsigned p2 = (unsigned)f2bf(f0.z) | ((unsigned)f2bf(f1.z) << 16);
                unsigned p3 = (unsigned)f2bf(f0.w) | ((unsigned)f2bf(f1.w) << 16);
                *(unsigned*)&Bt[(dq + 0) * 72 + col] = p0;
                *(unsigned*)&Bt[(dq + 1) * 72 + col] = p1;
                *(unsigned*)&Bt[(dq + 2) * 72 + col] = p2;
                *(unsigned*)&Bt[(dq + 3) * 72 + col] = p3;
            }
            __syncthreads();
            s16x8 af[4][2], bfr[2];
            #pragma unroll
            for (int fm = 0; fm < 4; ++fm)
                #pragma unroll
                for (int c2 = 0; c2 < 2; ++c2)
                    af[fm][c2] = *(const s16x8*)&At[(fm * 16 + l16) * 72 + c2 * 32 + k8 * 8];
            #pragma unroll
            for (int c2 = 0; c2 < 2; ++c2)
                bfr[c2] = *(const s16x8*)&Bt[((w << 4) + l16) * 72 + c2 * 32
                                             + ((k8 ^ (l16 >> 2)) << 3)];
            #pragma unroll
            for (int fm = 0; fm < 4; ++fm)
                #pragma unroll
                for (int c2 = 0; c2 < 2; ++c2)
                    acc[fm] = __builtin_amdgcn_mfma_f32_16x16x32_bf16(af[fm][c2], bfr[c2], acc[fm], 0, 0, 0);
        }
        #pragma unroll
        for (int fm = 0; fm < 4; ++fm)
            #pragma unroll
            for (int j = 0; j < 4; ++j) {
                int r = fm * 16 + k8 * 4 + j;
                int c = (w << 4) + l16;
                outp[((size_t)(b * 64 + r)) * 2048 + d0 + c] = f2bf(acc[fm][j]);
            }
    } else if (bid < 5120) {
        // ---------------- weight transpose + cast 64x64 ----------------
        u16* tl = (u16*)smem;            // [64][68]
        int wb = bid - 2048;
        int which = wb >> 10;
        int t = wb & 1023;
        const float* in = which == 0 ? w0 : which == 1 ? w1 : w2;
        u16* out        = which == 0 ? o0 : which == 1 ? o1 : o2;
        int bx = (t & 31) * 64, by = (t >> 5) * 64;
        int tx = tid & 63, ty = tid >> 6;
        #pragma unroll 4
        for (int i = ty; i < 64; i += 4)
            tl[tx * 68 + i] = f2bf(in[(size_t)(by + i) * 2048 + bx + tx]);
        __syncthreads();
        int srow = tid >> 2, sq = tid & 3;
        const u16* lp = &tl[srow * 68 + sq * 16];
        u16* op = &out[(size_t)(bx + srow) * 2048 + by + sq * 16];
        #pragma unroll
        for (int j8 = 0; j8 < 4; ++j8)
            *(short4*)(op + j8 * 4) = *(const short4*)(lp + j8 * 4);
    } else {
        // ---------------- q cast ----------------
        int cb = bid - 5120;
        size_t base = (size_t)cb * 256 + tid;
        #pragma unroll
        for (int it = 0; it < 8; ++it) {
            size_t i = base + (size_t)it * 1048576;
            float4 f = ((const float4*)q)[i];
            ushort4 o;
            o.x = f2bf(f.x); o.y = f2bf(f.y); o.z = f2bf(f.z); o.w = f2bf(f.w);
            ((ushort4*)qb)[i] = o;
        }
    }
}

// ---------------------------------------------------------------------------
// 128x128 bf16 GEMM, dual: z=0: phik=elu(kds@wkT)+1; z=1: vals=vds@wvT
// ---------------------------------------------------------------------------
__global__ __launch_bounds__(256) void gemm128_dual(
    const u16* __restrict__ A0, const u16* __restrict__ B0, u16* __restrict__ C0,
    const u16* __restrict__ A1, const u16* __restrict__ B1, u16* __restrict__ C1)
{
    const u16* A  = blockIdx.z ? A1 : A0;
    const u16* BT = blockIdx.z ? B1 : B0;
    u16* C        = blockIdx.z ? C1 : C0;
    const bool elu = (blockIdx.z == 0);
    const int K = 2048;

    __shared__ __align__(16) u16 lds[2][8192];
    const int tid = threadIdx.x;
    const int w = tid >> 6, l = tid & 63;
    const int wm = w >> 1, wn = w & 1;
    const int l16 = l & 15, k8 = l >> 4;
    const int sr = (w << 4) + (l >> 2);
    const int sc = (l & 3) << 3;
    const int row0 = blockIdx.y * 128, col0 = blockIdx.x * 128;
    const int nk = K >> 5;
    f32x4 acc[4][4] = {};

#define STAGE(buf, kt) do {                                                        \
        int kk0 = (kt) << 5;                                                       \
        _Pragma("unroll")                                                          \
        for (int i = 0; i < 2; ++i) {                                              \
            const u16* ga = A + (size_t)(row0 + i * 64 + sr) * K + kk0 + sc;       \
            async16(&lds[buf][i * 2048 + (w << 9)], ga);                           \
            const u16* gb = BT + (size_t)(col0 + i * 64 + sr) * K + kk0 + sc;      \
            async16(&lds[buf][4096 + i * 2048 + (w << 9)], gb);                    \
        }                                                                          \
    } while (0)

    STAGE(0, 0);
    asm volatile("s_waitcnt vmcnt(0)" ::: "memory");
    __syncthreads();
    int cur = 0;
    for (int kt = 0; kt < nk; ++kt) {
        if (kt + 1 < nk) STAGE(cur ^ 1, kt + 1);
        s16x8 af[4], bfr[4];
        const u16* Ab = &lds[cur][0];
        const u16* Bb = &lds[cur][4096];
        #pragma unroll
        for (int fm = 0; fm < 4; ++fm)
            af[fm] = *(const s16x8*)&Ab[((wm << 6) + (fm << 4) + l16) * 32 + (k8 << 3)];
        #pragma unroll
        for (int fn = 0; fn < 4; ++fn)
            bfr[fn] = *(const s16x8*)&Bb[((wn << 6) + (fn << 4) + l16) * 32 + (k8 << 3)];
        #pragma unroll
        for (int fm = 0; fm < 4; ++fm)
            #pragma unroll
            for (int fn = 0; fn < 4; ++fn)
                acc[fm][fn] = __builtin_amdgcn_mfma_f32_16x16x32_bf16(af[fm], bfr[fn], acc[fm][fn], 0, 0, 0);
        __syncthreads();
        cur ^= 1;
    }
#undef STAGE

    #pragma unroll
    for (int fm = 0; fm < 4; ++fm)
        #pragma unroll
        for (int j = 0; j < 4; ++j) {
            int r = row0 + (wm << 6) + (fm << 4) + (k8 << 2) + j;
            size_t rbase = (size_t)r * 2048;
            #pragma unroll
            for (int fn = 0; fn < 4; ++fn) {
                int c = col0 + (wn << 6) + (fn << 4) + l16;
                float x = acc[fm][fn][j];
                if (elu) x = x > 0.0f ? x + 1.0f : __expf(x);
                C[rbase + c] = f2bf(x);
            }
        }
}

// ---------------------------------------------------------------------------
// s & z per (b,n): sT bf16 [B,N,128,128], z fp32 [B,N,128]  (R8-verified)
// ---------------------------------------------------------------------------
__global__ __launch_bounds__(256) void sz_kernel(
    const u16* __restrict__ phik, const u16* __restrict__ vals,
    u16* __restrict__ sT, float* __restrict__ z)
{
    int b = blockIdx.x >> 4, n = blockIdx.x & 15;
    __shared__ __align__(16) u16 pk[64 * 128];
    __shared__ __align__(16) u16 vv[64 * 128];
    int tid = threadIdx.x;
    for (int i = tid; i < 1024; i += 256) {
        int r = i >> 4, c8 = (i & 15) << 3;
        size_t g = ((size_t)(b * 64 + r)) * 2048 + n * 128 + c8;
        ((s16x8*)pk)[i] = *(const s16x8*)&phik[g];
        ((s16x8*)vv)[i] = *(const s16x8*)&vals[g];
    }
    __syncthreads();
    if (tid < 128) {
        float s = 0.0f;
        for (int kk = 0; kk < 64; ++kk) s += bf2f(pk[kk * 128 + tid]);
        z[((size_t)(b * 16 + n)) * 128 + tid] = s;
    }
    int hg = tid >> 4, dg = tid & 15;
    int h0 = hg * 8, d0 = dg * 8;
    float acc[8][8] = {};
    for (int kk = 0; kk < 64; ++kk) {
        s16x8 vr = *(const s16x8*)&vv[kk * 128 + h0];
        s16x8 pr = *(const s16x8*)&pk[kk * 128 + d0];
        float va[8], pa[8];
        #pragma unroll
        for (int i = 0; i < 8; ++i) { va[i] = bf2f((u16)vr[i]); pa[i] = bf2f((u16)pr[i]); }
        #pragma unroll
        for (int i = 0; i < 8; ++i)
            #pragma unroll
            for (int j = 0; j < 8; ++j)
                acc[i][j] += va[i] * pa[j];
    }
    size_t base = ((size_t)(b * 16 + n)) * 16384;
    #pragma unroll
    for (int i = 0; i < 8; ++i) {
        u16 row[8];
        #pragma unroll
        for (int j = 0; j < 8; ++j) row[j] = f2bf(acc[i][j]);
        *(s16x8*)&sT[base + (size_t)(h0 + i) * 128 + d0] = *(s16x8*)row;
    }
}

// ---------------------------------------------------------------------------
// gemm256_qs: 256x256 8-phase bf16 GEMM (phi_q) with FUSED qs epilogue v2.
// (R14-verified: P-half + sT tile staged in LDS, qz via broadcast-z MFMA.)
// ---------------------------------------------------------------------------
__global__ __launch_bounds__(512, 2) void gemm256_qs(
    const u16* __restrict__ A, const u16* __restrict__ BT,
    const u16* __restrict__ sT, const float* __restrict__ z,
    float* __restrict__ outp)
{
    const int K = 2048, NT = 32, nbn = 8;
    __shared__ __align__(16) u16 lds[8][8192];
    const int tid = threadIdx.x;
    const int w = tid >> 6, l = tid & 63;
    const int wm = w >> 2, wn = w & 3;
    const int l16 = l & 15, k8 = l >> 4;

    const int nwg = gridDim.x;
    int wg = blockIdx.x;
    if ((nwg & 7) == 0) wg = (wg & 7) * (nwg >> 3) + (wg >> 3);
    const int row0 = (wg / nbn) << 8, col0 = (wg % nbn) << 8;

    const int lr  = l >> 3;
    const int scb = (((l & 7) ^ lr) << 4);
    const int swzr = (l16 & 7) << 4;

#define PANEL(s, m, h) (&lds[((s) << 2) | ((m) << 1) | (h)][0])

#define STG(pan, G, prow0, kk0) do {                                             \
        _Pragma("unroll")                                                        \
        for (int i_ = 0; i_ < 2; ++i_) {                                         \
            int seg_ = w + (i_ << 3);                                            \
            const u16* src_ = (G) + (size_t)((prow0) + (seg_ << 3) + lr) * K     \
                              + (kk0) + (scb >> 1);                              \
            async16((pan) + (seg_ << 9), src_);                                  \
        } } while (0)

#define LDA(slot, mh) do { const u16* p_ = PANEL(slot, 0, mh);                   \
        _Pragma("unroll")                                                        \
        for (int fm_ = 0; fm_ < 4; ++fm_)                                        \
        _Pragma("unroll")                                                        \
        for (int ks_ = 0; ks_ < 2; ++ks_)                                        \
            Af[fm_][ks_] = *(const s16x8*)(p_ + (wm * 64 + fm_ * 16 + l16) * 64  \
                           + (((ks_ * 64 + k8 * 16) ^ swzr) >> 1)); } while (0)

#define LDB(slot, nh, dst) do { const u16* p_ = PANEL(slot, 1, nh);              \
        _Pragma("unroll")                                                        \
        for (int fn_ = 0; fn_ < 2; ++fn_)                                        \
        _Pragma("unroll")                                                        \
        for (int ks_ = 0; ks_ < 2; ++ks_)                                        \
            dst[fn_][ks_] = *(const s16x8*)(p_ + (wn * 32 + fn_ * 16 + l16) * 64 \
                           + (((ks_ * 64 + k8 * 16) ^ swzr) >> 1)); } while (0)

#define MM(mh, nh, BF) do {                                                      \
        __builtin_amdgcn_s_setprio(1);                                           \
        _Pragma("unroll")                                                        \
        for (int fm_ = 0; fm_ < 4; ++fm_)                                        \
        _Pragma("unroll")                                                        \
        for (int fn_ = 0; fn_ < 2; ++fn_)                                        \
        _Pragma("unroll")                                                        \
        for (int ks_ = 0; ks_ < 2; ++ks_)                                        \
            acc[mh][nh][fm_][fn_] = __builtin_amdgcn_mfma_f32_16x16x32_bf16(     \
                Af[fm_][ks_], BF[fn_][ks_], acc[mh][nh][fm_][fn_], 0, 0, 0);     \
        __builtin_amdgcn_s_setprio(0); } while (0)

#define TILE(t, cur, nxt, BFc, BFn) do {                                         \
        LDA(cur, 0);                                                             \
        if ((t) + 1 < NT) STG(PANEL(nxt, 0, 1), A, row0 + 128, ((t) + 1) << 6);  \
        BARRIER(); MM(0, 0, BFc); BARRIER();                                     \
        LDB(cur, 1, Bf1);                                                        \
        if ((t) + 2 < NT) STG(PANEL(cur, 0, 0), A, row0, ((t) + 2) << 6);        \
        BARRIER(); MM(0, 1, Bf1); BARRIER();                                     \
        LDA(cur, 1);                                                             \
        if ((t) + 2 < NT) STG(PANEL(cur, 1, 0), BT, col0, ((t) + 2) << 6);       \
        BARRIER(); MM(1, 1, Bf1); BARRIER();                                     \
        if ((t) + 2 < NT) STG(PANEL(cur, 1, 1), BT, col0 + 128, ((t) + 2) << 6); \
        BARRIER(); MM(1, 0, BFc);                                                \
        if ((t) == NT - 2)     asm volatile("s_waitcnt vmcnt(0)" ::: "memory");  \
        else if ((t) < NT - 2) asm volatile("s_waitcnt vmcnt(6)" ::: "memory");  \
        BARRIER();                                                               \
        if ((t) + 1 < NT) LDB(nxt, 0, BFn);                                      \
    } while (0)

    f32x4 acc[2][2][4][2] = {};
    s16x8 Af[4][2], Bf0a[2][2], Bf0b[2][2], Bf1[2][2];

    STG(PANEL(0, 0, 0), A,  row0,       0);
    STG(PANEL(0, 1, 0), BT, col0,       0);
    STG(PANEL(0, 1, 1), BT, col0 + 128, 0);
    STG(PANEL(0, 0, 1), A,  row0 + 128, 0);
    STG(PANEL(1, 0, 0), A,  row0,       64);
    STG(PANEL(1, 1, 0), BT, col0,       64);
    STG(PANEL(1, 1, 1), BT, col0 + 128, 64);
    asm volatile("s_waitcnt vmcnt(6)" ::: "memory");
    BARRIER();
    LDB(0, 0, Bf0a);

    for (int t = 0; t < NT; t += 2) {
        TILE(t,     0, 1, Bf0a, Bf0b);
        TILE(t + 1, 1, 0, Bf0b, Bf0a);
    }
#undef PANEL
#undef STG
#undef LDA
#undef LDB
#undef MM
#undef TILE

    // ---- fused qs epilogue v2 ----
    const int b = row0 >> 9;
    const int n0 = col0 >> 7;
    u16* Ph  = &lds[0][0];              // [256][128] swizzled P half
    u16* sTl = &lds[4][0];              // [128][128] swizzled sT tile

    #pragma unroll
    for (int nsel = 0; nsel < 2; ++nsel) {
        #pragma unroll
        for (int mh = 0; mh < 2; ++mh)
            #pragma unroll
            for (int fm = 0; fm < 4; ++fm)
                #pragma unroll
                for (int j = 0; j < 4; ++j) {
                    int rr = mh * 128 + wm * 64 + fm * 16 + k8 * 4 + j;
                    int rowbase = rr << 7;
                    int msk = ((rr >> 2) & 7) << 4;
                    #pragma unroll
                    for (int fn = 0; fn < 2; ++fn) {
                        int cc = wn * 32 + fn * 16 + l16;
                        float x = acc[mh][nsel][fm][fn][j];
                        x = x > 0.0f ? x + 1.0f : __expf(x);
                        Ph[rowbase + (cc ^ msk)] = f2bf(x);
                    }
                }
        {
            const size_t stb = ((size_t)(b * 16 + n0 + nsel)) << 14;
            #pragma unroll
            for (int it = 0; it < 4; ++it) {
                int g = (it << 12) + (tid << 3);
                int row = g >> 7;
                int ch8 = (g >> 3) & 15;
                const u16* src = sT + stb + (row << 7) + ((ch8 ^ (row & 7)) << 3);
                async16(&sTl[g], src);
            }
        }
        __syncthreads();

        const int nn = n0 + nsel;
        const float* zp0 = z + ((size_t)(b * 16 + nn) << 7);
        s16x8 Bz[4];
        #pragma unroll
        for (int ks = 0; ks < 4; ++ks) {
            const float* zp = zp0 + (ks << 5) + (k8 << 3);
            float4 f0 = *(const float4*)zp;
            float4 f1 = *(const float4*)(zp + 4);
            u16 tmp[8] = { f2bf(f0.x), f2bf(f0.y), f2bf(f0.z), f2bf(f0.w),
                           f2bf(f1.x), f2bf(f1.y), f2bf(f1.z), f2bf(f1.w) };
            Bz[ks] = *(const s16x8*)tmp;
        }

        s16x8 Af2[2][4];
        #pragma unroll
        for (int fm2 = 0; fm2 < 2; ++fm2) {
            int rr = (w << 5) + (fm2 << 4) + l16;
            int rowbase = rr << 7;
            int msk = ((rr >> 2) & 7) << 4;
            #pragma unroll
            for (int ks = 0; ks < 4; ++ks) {
                int cc = (ks << 5) + (k8 << 3);
                Af2[fm2][ks] = *(const s16x8*)&Ph[rowbase + (cc ^ msk)];
            }
        }

        f32x4 accz[2] = {};
        #pragma unroll
        for (int fm2 = 0; fm2 < 2; ++fm2)
            #pragma unroll
            for (int ks = 0; ks < 4; ++ks)
                accz[fm2] = __builtin_amdgcn_mfma_f32_16x16x32_bf16(Af2[fm2][ks], Bz[ks], accz[fm2], 0, 0, 0);

        f32x4 acc2[2][8] = {};
        #pragma unroll
        for (int fn = 0; fn < 8; ++fn) {
            s16x8 Bfr[4];
            #pragma unroll
            for (int ks = 0; ks < 4; ++ks) {
                int rw = (fn << 4) + l16;
                Bfr[ks] = *(const s16x8*)&sTl[(rw << 7)
                            + (((ks << 5) + (k8 << 3)) ^ ((rw & 7) << 3))];
            }
            #pragma unroll
            for (int fm2 = 0; fm2 < 2; ++fm2)
                #pragma unroll
                for (int ks = 0; ks < 4; ++ks)
                    acc2[fm2][fn] = __builtin_amdgcn_mfma_f32_16x16x32_bf16(Af2[fm2][ks], Bfr[ks], acc2[fm2][fn], 0, 0, 0);
        }

        #pragma unroll
        for (int fm2 = 0; fm2 < 2; ++fm2)
            #pragma unroll
            for (int j = 0; j < 4; ++j) {
                int grow = row0 + (w << 5) + (fm2 << 4) + (k8 << 2) + j;
                float rq = 1.0f / (accz[fm2][j] + EPS);
                size_t ob = (size_t)grow * 2048 + col0 + (nsel << 7);
                #pragma unroll
                for (int fn = 0; fn < 8; ++fn)
                    outp[ob + (fn << 4) + l16] = acc2[fm2][fn][j] * rq;
            }
        __syncthreads();
    }
}

// ---------------------------------------------------------------------------
extern "C" void kernel_launch(void* const* d_in, const int* in_sizes, int n_in,
                              void* d_out, int out_size, void* d_ws, size_t ws_size,
                              hipStream_t stream) {
    (void)in_sizes; (void)n_in; (void)out_size; (void)ws_size;
    const float* q   = (const float*)d_in[0];
    const float* k   = (const float*)d_in[1];
    const float* v   = (const float*)d_in[2];
    const float* wq  = (const float*)d_in[3];
    const float* wk  = (const float*)d_in[4];
    const float* wv  = (const float*)d_in[5];
    const float* kdw = (const float*)d_in[6];
    const float* vdw = (const float*)d_in[7];
    float* out = (float*)d_out;

    char* p = (char*)d_ws;
    u16* qb   = (u16*)p; p += (size_t)16384 * 2048 * 2;
    u16* wqT  = (u16*)p; p += (size_t)2048 * 2048 * 2;
    u16* wkT  = (u16*)p; p += (size_t)2048 * 2048 * 2;
    u16* wvT  = (u16*)p; p += (size_t)2048 * 2048 * 2;
    u16* kds  = (u16*)p; p += (size_t)2048 * 2048 * 2;
    u16* vds  = (u16*)p; p += (size_t)2048 * 2048 * 2;
    u16* phik = (u16*)p; p += (size_t)2048 * 2048 * 2;
    u16* vals = (u16*)p; p += (size_t)2048 * 2048 * 2;
    u16* sT   = (u16*)p; p += (size_t)512 * 128 * 128 * 2;
    float* z  = (float*)p; p += (size_t)512 * 128 * 4;

    prep_down<<<9216, 256, 0, stream>>>(q, qb, wq, wk, wv, wqT, wkT, wvT,
                                        k, v, kdw, vdw, kds, vds);
    gemm128_dual<<<dim3(16, 16, 2), 256, 0, stream>>>(kds, wkT, phik, vds, wvT, vals);
    sz_kernel<<<512, 256, 0, stream>>>(phik, vals, sT, z);
    gemm256_qs<<<512, 512, 0, stream>>>(qb, wqT, sT, z, out);
}

// Round 19
// 342.060 us; speedup vs baseline: 1.0378x; 1.0002x over previous
//
#include <hip/hip_runtime.h>
#include <cstdint>
#include <cstddef>

typedef float f32x4 __attribute__((ext_vector_type(4)));
typedef short s16x8 __attribute__((ext_vector_type(8)));
typedef unsigned short u16;

#define EPS 1e-6f

__device__ __forceinline__ u16 f2bf(float f) {
    unsigned u = __float_as_uint(f);
    u += 0x7FFFu + ((u >> 16) & 1u);
    return (u16)(u >> 16);
}
__device__ __forceinline__ float bf2f(u16 u) {
    return __uint_as_float(((unsigned)u) << 16);
}

typedef const __attribute__((address_space(1))) void cg_void;
typedef __attribute__((address_space(3))) void l_void;
__device__ __forceinline__ void async16(void* dst_lds, const void* src_g) {
    __builtin_amdgcn_global_load_lds((cg_void*)src_g, (l_void*)dst_lds, 16, 0, 0);
}

#define BARRIER() do { asm volatile("" ::: "memory"); \
                       __builtin_amdgcn_s_barrier();  \
                       asm volatile("" ::: "memory"); } while (0)

// ---------------------------------------------------------------------------
// prep_down: all preprocessing in one launch (9216 blocks) — R18-verified.
//   [0,2048):     downsample via MFMA, K-step 64, At/Bt [64][72]
//   [2048,5120):  weight transpose+cast 64x64 tiles
//   [5120,9216):  q cast fp32->bf16
// ---------------------------------------------------------------------------
__global__ __launch_bounds__(256) void prep_down(
    const float* __restrict__ q, u16* __restrict__ qb,
    const float* __restrict__ w0, const float* __restrict__ w1,
    const float* __restrict__ w2, u16* __restrict__ o0,
    u16* __restrict__ o1, u16* __restrict__ o2,
    const float* __restrict__ kin, const float* __restrict__ vin,
    const float* __restrict__ wdk, const float* __restrict__ wdv,
    u16* __restrict__ kds, u16* __restrict__ vds)
{
    __shared__ __align__(16) char smem[18432];
    const int bid = blockIdx.x;
    const int tid = threadIdx.x;

    if (bid < 2048) {
        u16* At = (u16*)smem;            // [64][72]
        u16* Bt = (u16*)(smem + 9216);   // [64][72] XOR-swizzled per 32-chunk
        const int sel = bid >> 10, rem = bid & 1023;
        const int b = rem >> 5, d0 = (rem & 31) << 6;
        const float* x  = sel ? vin : kin;
        const float* wd = sel ? wdv : wdk;
        u16* outp       = sel ? vds : kds;
        const int w = tid >> 6, l = tid & 63, l16 = l & 15, k8 = l >> 4;
        f32x4 acc[4];
        #pragma unroll
        for (int fm = 0; fm < 4; ++fm) acc[fm] = (f32x4){0.f, 0.f, 0.f, 0.f};
        for (int s0 = 0; s0 < 512; s0 += 64) {
            __syncthreads();
            #pragma unroll
            for (int u = 0; u < 4; ++u) {            // A: 64 rows x 16 quads
                int c = tid + (u << 8);
                int kkr = c >> 4, sc = (c & 15) << 2;
                float4 f = *(const float4*)&wd[kkr * 512 + s0 + sc];
                u16* dst = &At[kkr * 72 + sc];
                dst[0] = f2bf(f.x); dst[1] = f2bf(f.y); dst[2] = f2bf(f.z); dst[3] = f2bf(f.w);
            }
            #pragma unroll
            for (int u = 0; u < 2; ++u) {            // B: 32 s-pairs x 16 d-quads
                int c = tid + (u << 8);
                int sp = c >> 4, dq = (c & 15) << 2;
                int srow = sp << 1;
                const float* xp = &x[((size_t)(b * 512) + s0 + srow) * 2048 + d0 + dq];
                float4 f0 = *(const float4*)xp;
                float4 f1 = *(const float4*)(xp + 2048);
                int col = (srow & 32) | ((srow & 31) ^ ((c & 3) << 3));
                unsigned p0 = (unsigned)f2bf(f0.x) | ((unsigned)f2bf(f1.x) << 16);
                unsigned p1 = (unsigned)f2bf(f0.y) | ((unsigned)f2bf(f1.y) << 16);
                unsigned p2 = (unsigned)f2bf(f0.z) | ((unsigned)f2bf(f1.z) << 16);
                unsigned p3 = (unsigned)f2bf(f0.w) | ((unsigned)f2bf(f1.w) << 16);
                *(unsigned*)&Bt[(dq + 0) * 72 + col] = p0;
                *(unsigned*)&Bt[(dq + 1) * 72 + col] = p1;
                *(unsigned*)&Bt[(dq + 2) * 72 + col] = p2;
                *(unsigned*)&Bt[(dq + 3) * 72 + col] = p3;
            }
            __syncthreads();
            s16x8 af[4][2], bfr[2];
            #pragma unroll
            for (int fm = 0; fm < 4; ++fm)
                #pragma unroll
                for (int c2 = 0; c2 < 2; ++c2)
                    af[fm][c2] = *(const s16x8*)&At[(fm * 16 + l16) * 72 + c2 * 32 + k8 * 8];
            #pragma unroll
            for (int c2 = 0; c2 < 2; ++c2)
                bfr[c2] = *(const s16x8*)&Bt[((w << 4) + l16) * 72 + c2 * 32
                                             + ((k8 ^ (l16 >> 2)) << 3)];
            #pragma unroll
            for (int fm = 0; fm < 4; ++fm)
                #pragma unroll
                for (int c2 = 0; c2 < 2; ++c2)
                    acc[fm] = __builtin_amdgcn_mfma_f32_16x16x32_bf16(af[fm][c2], bfr[c2], acc[fm], 0, 0, 0);
        }
        #pragma unroll
        for (int fm = 0; fm < 4; ++fm)
            #pragma unroll
            for (int j = 0; j < 4; ++j) {
                int r = fm * 16 + k8 * 4 + j;
                int c = (w << 4) + l16;
                outp[((size_t)(b * 64 + r)) * 2048 + d0 + c] = f2bf(acc[fm][j]);
            }
    } else if (bid < 5120) {
        u16* tl = (u16*)smem;            // [64][68]
        int wb = bid - 2048;
        int which = wb >> 10;
        int t = wb & 1023;
        const float* in = which == 0 ? w0 : which == 1 ? w1 : w2;
        u16* out        = which == 0 ? o0 : which == 1 ? o1 : o2;
        int bx = (t & 31) * 64, by = (t >> 5) * 64;
        int tx = tid & 63, ty = tid >> 6;
        #pragma unroll 4
        for (int i = ty; i < 64; i += 4)
            tl[tx * 68 + i] = f2bf(in[(size_t)(by + i) * 2048 + bx + tx]);
        __syncthreads();
        int srow = tid >> 2, sq = tid & 3;
        const u16* lp = &tl[srow * 68 + sq * 16];
        u16* op = &out[(size_t)(bx + srow) * 2048 + by + sq * 16];
        #pragma unroll
        for (int j8 = 0; j8 < 4; ++j8)
            *(short4*)(op + j8 * 4) = *(const short4*)(lp + j8 * 4);
    } else {
        int cb = bid - 5120;
        size_t base = (size_t)cb * 256 + tid;
        #pragma unroll
        for (int it = 0; it < 8; ++it) {
            size_t i = base + (size_t)it * 1048576;
            float4 f = ((const float4*)q)[i];
            ushort4 o;
            o.x = f2bf(f.x); o.y = f2bf(f.y); o.z = f2bf(f.z); o.w = f2bf(f.w);
            ((ushort4*)qb)[i] = o;
        }
    }
}

// ---------------------------------------------------------------------------
// 128x128 bf16 GEMM, dual: z=0: phik=elu(kds@wkT)+1; z=1: vals=vds@wvT
// ---------------------------------------------------------------------------
__global__ __launch_bounds__(256) void gemm128_dual(
    const u16* __restrict__ A0, const u16* __restrict__ B0, u16* __restrict__ C0,
    const u16* __restrict__ A1, const u16* __restrict__ B1, u16* __restrict__ C1)
{
    const u16* A  = blockIdx.z ? A1 : A0;
    const u16* BT = blockIdx.z ? B1 : B0;
    u16* C        = blockIdx.z ? C1 : C0;
    const bool elu = (blockIdx.z == 0);
    const int K = 2048;

    __shared__ __align__(16) u16 lds[2][8192];
    const int tid = threadIdx.x;
    const int w = tid >> 6, l = tid & 63;
    const int wm = w >> 1, wn = w & 1;
    const int l16 = l & 15, k8 = l >> 4;
    const int sr = (w << 4) + (l >> 2);
    const int sc = (l & 3) << 3;
    const int row0 = blockIdx.y * 128, col0 = blockIdx.x * 128;
    const int nk = K >> 5;
    f32x4 acc[4][4] = {};

#define STAGE(buf, kt) do {                                                        \
        int kk0 = (kt) << 5;                                                       \
        _Pragma("unroll")                                                          \
        for (int i = 0; i < 2; ++i) {                                              \
            const u16* ga = A + (size_t)(row0 + i * 64 + sr) * K + kk0 + sc;       \
            async16(&lds[buf][i * 2048 + (w << 9)], ga);                           \
            const u16* gb = BT + (size_t)(col0 + i * 64 + sr) * K + kk0 + sc;      \
            async16(&lds[buf][4096 + i * 2048 + (w << 9)], gb);                    \
        }                                                                          \
    } while (0)

    STAGE(0, 0);
    asm volatile("s_waitcnt vmcnt(0)" ::: "memory");
    __syncthreads();
    int cur = 0;
    for (int kt = 0; kt < nk; ++kt) {
        if (kt + 1 < nk) STAGE(cur ^ 1, kt + 1);
        s16x8 af[4], bfr[4];
        const u16* Ab = &lds[cur][0];
        const u16* Bb = &lds[cur][4096];
        #pragma unroll
        for (int fm = 0; fm < 4; ++fm)
            af[fm] = *(const s16x8*)&Ab[((wm << 6) + (fm << 4) + l16) * 32 + (k8 << 3)];
        #pragma unroll
        for (int fn = 0; fn < 4; ++fn)
            bfr[fn] = *(const s16x8*)&Bb[((wn << 6) + (fn << 4) + l16) * 32 + (k8 << 3)];
        #pragma unroll
        for (int fm = 0; fm < 4; ++fm)
            #pragma unroll
            for (int fn = 0; fn < 4; ++fn)
                acc[fm][fn] = __builtin_amdgcn_mfma_f32_16x16x32_bf16(af[fm], bfr[fn], acc[fm][fn], 0, 0, 0);
        __syncthreads();
        cur ^= 1;
    }
#undef STAGE

    #pragma unroll
    for (int fm = 0; fm < 4; ++fm)
        #pragma unroll
        for (int j = 0; j < 4; ++j) {
            int r = row0 + (wm << 6) + (fm << 4) + (k8 << 2) + j;
            size_t rbase = (size_t)r * 2048;
            #pragma unroll
            for (int fn = 0; fn < 4; ++fn) {
                int c = col0 + (wn << 6) + (fn << 4) + l16;
                float x = acc[fm][fn][j];
                if (elu) x = x > 0.0f ? x + 1.0f : __expf(x);
                C[rbase + c] = f2bf(x);
            }
        }
}

// ---------------------------------------------------------------------------
// s & z per (b,n): sT bf16 [B,N,128,128], z fp32 [B,N,128]  (R8-verified)
// ---------------------------------------------------------------------------
__global__ __launch_bounds__(256) void sz_kernel(
    const u16* __restrict__ phik, const u16* __restrict__ vals,
    u16* __restrict__ sT, float* __restrict__ z)
{
    int b = blockIdx.x >> 4, n = blockIdx.x & 15;
    __shared__ __align__(16) u16 pk[64 * 128];
    __shared__ __align__(16) u16 vv[64 * 128];
    int tid = threadIdx.x;
    for (int i = tid; i < 1024; i += 256) {
        int r = i >> 4, c8 = (i & 15) << 3;
        size_t g = ((size_t)(b * 64 + r)) * 2048 + n * 128 + c8;
        ((s16x8*)pk)[i] = *(const s16x8*)&phik[g];
        ((s16x8*)vv)[i] = *(const s16x8*)&vals[g];
    }
    __syncthreads();
    if (tid < 128) {
        float s = 0.0f;
        for (int kk = 0; kk < 64; ++kk) s += bf2f(pk[kk * 128 + tid]);
        z[((size_t)(b * 16 + n)) * 128 + tid] = s;
    }
    int hg = tid >> 4, dg = tid & 15;
    int h0 = hg * 8, d0 = dg * 8;
    float acc[8][8] = {};
    for (int kk = 0; kk < 64; ++kk) {
        s16x8 vr = *(const s16x8*)&vv[kk * 128 + h0];
        s16x8 pr = *(const s16x8*)&pk[kk * 128 + d0];
        float va[8], pa[8];
        #pragma unroll
        for (int i = 0; i < 8; ++i) { va[i] = bf2f((u16)vr[i]); pa[i] = bf2f((u16)pr[i]); }
        #pragma unroll
        for (int i = 0; i < 8; ++i)
            #pragma unroll
            for (int j = 0; j < 8; ++j)
                acc[i][j] += va[i] * pa[j];
    }
    size_t base = ((size_t)(b * 16 + n)) * 16384;
    #pragma unroll
    for (int i = 0; i < 8; ++i) {
        u16 row[8];
        #pragma unroll
        for (int j = 0; j < 8; ++j) row[j] = f2bf(acc[i][j]);
        *(s16x8*)&sT[base + (size_t)(h0 + i) * 128 + d0] = *(s16x8*)row;
    }
}

// ---------------------------------------------------------------------------
// gemm256_qs: 256x256 8-phase bf16 GEMM (phi_q) with FUSED qs epilogue v3.
// v3: BOTH heads' sT tiles pre-staged into sTl/sTl2 (lds[4..5]/[6..7], free
// after the K-loop) immediately after the last K-loop barrier — both drain
// at the first __syncthreads (needed for Ph anyway); nsel=1 runs with zero
// staging latency. Pure reorder of independent async ops; barriers unchanged.
// ---------------------------------------------------------------------------
__global__ __launch_bounds__(512, 2) void gemm256_qs(
    const u16* __restrict__ A, const u16* __restrict__ BT,
    const u16* __restrict__ sT, const float* __restrict__ z,
    float* __restrict__ outp)
{
    const int K = 2048, NT = 32, nbn = 8;
    __shared__ __align__(16) u16 lds[8][8192];
    const int tid = threadIdx.x;
    const int w = tid >> 6, l = tid & 63;
    const int wm = w >> 2, wn = w & 3;
    const int l16 = l & 15, k8 = l >> 4;

    const int nwg = gridDim.x;
    int wg = blockIdx.x;
    if ((nwg & 7) == 0) wg = (wg & 7) * (nwg >> 3) + (wg >> 3);
    const int row0 = (wg / nbn) << 8, col0 = (wg % nbn) << 8;

    const int lr  = l >> 3;
    const int scb = (((l & 7) ^ lr) << 4);
    const int swzr = (l16 & 7) << 4;

#define PANEL(s, m, h) (&lds[((s) << 2) | ((m) << 1) | (h)][0])

#define STG(pan, G, prow0, kk0) do {                                             \
        _Pragma("unroll")                                                        \
        for (int i_ = 0; i_ < 2; ++i_) {                                         \
            int seg_ = w + (i_ << 3);                                            \
            const u16* src_ = (G) + (size_t)((prow0) + (seg_ << 3) + lr) * K     \
                              + (kk0) + (scb >> 1);                              \
            async16((pan) + (seg_ << 9), src_);                                  \
        } } while (0)

#define LDA(slot, mh) do { const u16* p_ = PANEL(slot, 0, mh);                   \
        _Pragma("unroll")                                                        \
        for (int fm_ = 0; fm_ < 4; ++fm_)                                        \
        _Pragma("unroll")                                                        \
        for (int ks_ = 0; ks_ < 2; ++ks_)                                        \
            Af[fm_][ks_] = *(const s16x8*)(p_ + (wm * 64 + fm_ * 16 + l16) * 64  \
                           + (((ks_ * 64 + k8 * 16) ^ swzr) >> 1)); } while (0)

#define LDB(slot, nh, dst) do { const u16* p_ = PANEL(slot, 1, nh);              \
        _Pragma("unroll")                                                        \
        for (int fn_ = 0; fn_ < 2; ++fn_)                                        \
        _Pragma("unroll")                                                        \
        for (int ks_ = 0; ks_ < 2; ++ks_)                                        \
            dst[fn_][ks_] = *(const s16x8*)(p_ + (wn * 32 + fn_ * 16 + l16) * 64 \
                           + (((ks_ * 64 + k8 * 16) ^ swzr) >> 1)); } while (0)

#define MM(mh, nh, BF) do {                                                      \
        __builtin_amdgcn_s_setprio(1);                                           \
        _Pragma("unroll")                                                        \
        for (int fm_ = 0; fm_ < 4; ++fm_)                                        \
        _Pragma("unroll")                                                        \
        for (int fn_ = 0; fn_ < 2; ++fn_)                                        \
        _Pragma("unroll")                                                        \
        for (int ks_ = 0; ks_ < 2; ++ks_)                                        \
            acc[mh][nh][fm_][fn_] = __builtin_amdgcn_mfma_f32_16x16x32_bf16(     \
                Af[fm_][ks_], BF[fn_][ks_], acc[mh][nh][fm_][fn_], 0, 0, 0);     \
        __builtin_amdgcn_s_setprio(0); } while (0)

#define TILE(t, cur, nxt, BFc, BFn) do {                                         \
        LDA(cur, 0);                                                             \
        if ((t) + 1 < NT) STG(PANEL(nxt, 0, 1), A, row0 + 128, ((t) + 1) << 6);  \
        BARRIER(); MM(0, 0, BFc); BARRIER();                                     \
        LDB(cur, 1, Bf1);                                                        \
        if ((t) + 2 < NT) STG(PANEL(cur, 0, 0), A, row0, ((t) + 2) << 6);        \
        BARRIER(); MM(0, 1, Bf1); BARRIER();                                     \
        LDA(cur, 1);                                                             \
        if ((t) + 2 < NT) STG(PANEL(cur, 1, 0), BT, col0, ((t) + 2) << 6);       \
        BARRIER(); MM(1, 1, Bf1); BARRIER();                                     \
        if ((t) + 2 < NT) STG(PANEL(cur, 1, 1), BT, col0 + 128, ((t) + 2) << 6); \
        BARRIER(); MM(1, 0, BFc);                                                \
        if ((t) == NT - 2)     asm volatile("s_waitcnt vmcnt(0)" ::: "memory");  \
        else if ((t) < NT - 2) asm volatile("s_waitcnt vmcnt(6)" ::: "memory");  \
        BARRIER();                                                               \
        if ((t) + 1 < NT) LDB(nxt, 0, BFn);                                      \
    } while (0)

    f32x4 acc[2][2][4][2] = {};
    s16x8 Af[4][2], Bf0a[2][2], Bf0b[2][2], Bf1[2][2];

    STG(PANEL(0, 0, 0), A,  row0,       0);
    STG(PANEL(0, 1, 0), BT, col0,       0);
    STG(PANEL(0, 1, 1), BT, col0 + 128, 0);
    STG(PANEL(0, 0, 1), A,  row0 + 128, 0);
    STG(PANEL(1, 0, 0), A,  row0,       64);
    STG(PANEL(1, 1, 0), BT, col0,       64);
    STG(PANEL(1, 1, 1), BT, col0 + 128, 64);
    asm volatile("s_waitcnt vmcnt(6)" ::: "memory");
    BARRIER();
    LDB(0, 0, Bf0a);

    for (int t = 0; t < NT; t += 2) {
        TILE(t,     0, 1, Bf0a, Bf0b);
        TILE(t + 1, 1, 0, Bf0b, Bf0a);
    }
#undef PANEL
#undef STG
#undef LDA
#undef LDB
#undef MM
#undef TILE

    // ---- fused qs epilogue v3 ----
    const int b = row0 >> 9;
    const int n0 = col0 >> 7;
    u16* Ph   = &lds[0][0];             // [256][128] swizzled P half
    u16* sTl  = &lds[4][0];             // [128][128] swizzled sT tile (nsel=0)
    u16* sTl2 = &lds[6][0];             // [128][128] swizzled sT tile (nsel=1)

    // pre-stage BOTH heads' sT tiles (lds[4..7] free after K-loop; drains at
    // the first __syncthreads below)
    #pragma unroll
    for (int nsel = 0; nsel < 2; ++nsel) {
        const size_t stb = ((size_t)(b * 16 + n0 + nsel)) << 14;
        u16* dstl = nsel ? sTl2 : sTl;
        #pragma unroll
        for (int it = 0; it < 4; ++it) {
            int g = (it << 12) + (tid << 3);
            int row = g >> 7;
            int ch8 = (g >> 3) & 15;
            const u16* src = sT + stb + (row << 7) + ((ch8 ^ (row & 7)) << 3);
            async16(&dstl[g], src);
        }
    }

    #pragma unroll
    for (int nsel = 0; nsel < 2; ++nsel) {
        const u16* sTc = nsel ? sTl2 : sTl;
        // write P half = elu(acc[.][nsel])+1
        #pragma unroll
        for (int mh = 0; mh < 2; ++mh)
            #pragma unroll
            for (int fm = 0; fm < 4; ++fm)
                #pragma unroll
                for (int j = 0; j < 4; ++j) {
                    int rr = mh * 128 + wm * 64 + fm * 16 + k8 * 4 + j;
                    int rowbase = rr << 7;
                    int msk = ((rr >> 2) & 7) << 4;
                    #pragma unroll
                    for (int fn = 0; fn < 2; ++fn) {
                        int cc = wn * 32 + fn * 16 + l16;
                        float x = acc[mh][nsel][fm][fn][j];
                        x = x > 0.0f ? x + 1.0f : __expf(x);
                        Ph[rowbase + (cc ^ msk)] = f2bf(x);
                    }
                }
        __syncthreads();   // drains vmcnt (both sT stages) + lgkm (Ph writes)

        const int nn = n0 + nsel;
        const float* zp0 = z + ((size_t)(b * 16 + nn) << 7);
        s16x8 Bz[4];
        #pragma unroll
        for (int ks = 0; ks < 4; ++ks) {
            const float* zp = zp0 + (ks << 5) + (k8 << 3);
            float4 f0 = *(const float4*)zp;
            float4 f1 = *(const float4*)(zp + 4);
            u16 tmp[8] = { f2bf(f0.x), f2bf(f0.y), f2bf(f0.z), f2bf(f0.w),
                           f2bf(f1.x), f2bf(f1.y), f2bf(f1.z), f2bf(f1.w) };
            Bz[ks] = *(const s16x8*)tmp;
        }

        s16x8 Af2[2][4];
        #pragma unroll
        for (int fm2 = 0; fm2 < 2; ++fm2) {
            int rr = (w << 5) + (fm2 << 4) + l16;
            int rowbase = rr << 7;
            int msk = ((rr >> 2) & 7) << 4;
            #pragma unroll
            for (int ks = 0; ks < 4; ++ks) {
                int cc = (ks << 5) + (k8 << 3);
                Af2[fm2][ks] = *(const s16x8*)&Ph[rowbase + (cc ^ msk)];
            }
        }

        f32x4 accz[2] = {};
        #pragma unroll
        for (int fm2 = 0; fm2 < 2; ++fm2)
            #pragma unroll
            for (int ks = 0; ks < 4; ++ks)
                accz[fm2] = __builtin_amdgcn_mfma_f32_16x16x32_bf16(Af2[fm2][ks], Bz[ks], accz[fm2], 0, 0, 0);

        f32x4 acc2[2][8] = {};
        #pragma unroll
        for (int fn = 0; fn < 8; ++fn) {
            s16x8 Bfr[4];
            #pragma unroll
            for (int ks = 0; ks < 4; ++ks) {
                int rw = (fn << 4) + l16;
                Bfr[ks] = *(const s16x8*)&sTc[(rw << 7)
                            + (((ks << 5) + (k8 << 3)) ^ ((rw & 7) << 3))];
            }
            #pragma unroll
            for (int fm2 = 0; fm2 < 2; ++fm2)
                #pragma unroll
                for (int ks = 0; ks < 4; ++ks)
                    acc2[fm2][fn] = __builtin_amdgcn_mfma_f32_16x16x32_bf16(Af2[fm2][ks], Bfr[ks], acc2[fm2][fn], 0, 0, 0);
        }

        #pragma unroll
        for (int fm2 = 0; fm2 < 2; ++fm2)
            #pragma unroll
            for (int j = 0; j < 4; ++j) {
                int grow = row0 + (w << 5) + (fm2 << 4) + (k8 << 2) + j;
                float rq = 1.0f / (accz[fm2][j] + EPS);
                size_t ob = (size_t)grow * 2048 + col0 + (nsel << 7);
                #pragma unroll
                for (int fn = 0; fn < 8; ++fn)
                    outp[ob + (fn << 4) + l16] = acc2[fm2][fn][j] * rq;
            }
        __syncthreads();   // before next nsel overwrites Ph
    }
}

// ---------------------------------------------------------------------------
extern "C" void kernel_launch(void* const* d_in, const int* in_sizes, int n_in,
                              void* d_out, int out_size, void* d_ws, size_t ws_size,
                              hipStream_t stream) {
    (void)in_sizes; (void)n_in; (void)out_size; (void)ws_size;
    const float* q   = (const float*)d_in[0];
    const float* k   = (const float*)d_in[1];
    const float* v   = (const float*)d_in[2];
    const float* wq  = (const float*)d_in[3];
    const float* wk  = (const float*)d_in[4];
    const float* wv  = (const float*)d_in[5];
    const float* kdw = (const float*)d_in[6];
    const float* vdw = (const float*)d_in[7];
    float* out = (float*)d_out;

    char* p = (char*)d_ws;
    u16* qb   = (u16*)p; p += (size_t)16384 * 2048 * 2;
    u16* wqT  = (u16*)p; p += (size_t)2048 * 2048 * 2;
    u16* wkT  = (u16*)p; p += (size_t)2048 * 2048 * 2;
    u16* wvT  = (u16*)p; p += (size_t)2048 * 2048 * 2;
    u16* kds  = (u16*)p; p += (size_t)2048 * 2048 * 2;
    u16* vds  = (u16*)p; p += (size_t)2048 * 2048 * 2;
    u16* phik = (u16*)p; p += (size_t)2048 * 2048 * 2;
    u16* vals = (u16*)p; p += (size_t)2048 * 2048 * 2;
    u16* sT   = (u16*)p; p += (size_t)512 * 128 * 128 * 2;
    float* z  = (float*)p; p += (size_t)512 * 128 * 4;

    prep_down<<<9216, 256, 0, stream>>>(q, qb, wq, wk, wv, wqT, wkT, wvT,
                                        k, v, kdw, vdw, kds, vds);
    gemm128_dual<<<dim3(16, 16, 2), 256, 0, stream>>>(kds, wkT, phik, vds, wvT, vals);
    sz_kernel<<<512, 256, 0, stream>>>(phik, vals, sT, z);
    gemm256_qs<<<512, 512, 0, stream>>>(qb, wqT, sT, z, out);
}